// Round 1
// baseline (494.241 us; speedup 1.0000x reference)
//
#include <hip/hip_runtime.h>
#include <math.h>

#define NH   8
#define HD   64
#define BB   2
#define NQ   1024
#define NK   2048
#define RBH  64
#define TBLN 2048
#define TBL1 2049          // knots (need idx+1 at 2048)
#define DMAX 16.0f
#define INV_DT (TBLN / DMAX)   // 128 knots per unit distance

#define TQ 32
#define TK 32

// ---------------- bias lookup table: f_h(d) = (silu(d*W1+b1))@W2 + b2 ------
__global__ void bias_table_kernel(const float* __restrict__ W1,
                                  const float* __restrict__ b1,
                                  const float* __restrict__ W2,
                                  const float* __restrict__ b2,
                                  float* __restrict__ tbl) {
  int gid = blockIdx.x * blockDim.x + threadIdx.x;
  if (gid >= TBL1) return;
  float d = gid * (DMAX / TBLN);
  float acc[NH];
  #pragma unroll
  for (int h = 0; h < NH; h++) acc[h] = b2[h];
  for (int r = 0; r < RBH; r++) {
    float x = d * W1[r] + b1[r];
    float s = x / (1.0f + __expf(-x));   // silu
    #pragma unroll
    for (int h = 0; h < NH; h++) acc[h] += s * W2[r * NH + h];
  }
  #pragma unroll
  for (int h = 0; h < NH; h++) tbl[h * TBL1 + gid] = acc[h];
}

// ---------------- fp32 GEMM: C[M,512] = A[M,512] @ W[512,512] --------------
// grid = (M/64, 512/64), block = 256, each thread 4x4
__global__ __launch_bounds__(256) void gemm512(const float* __restrict__ A,
                                               const float* __restrict__ W,
                                               float* __restrict__ C) {
  __shared__ float As[16 * 68];   // [k][m], padded stride 68 (16B aligned)
  __shared__ float Ws[16 * 68];   // [k][n]
  const int t  = threadIdx.x;
  const int m0 = blockIdx.x * 64;
  const int n0 = blockIdx.y * 64;
  const int ty = t >> 4, tx = t & 15;
  const int lm = t >> 2, lk4 = (t & 3) * 4;   // A-tile load map
  const int wk = t >> 4, wn4 = (t & 15) * 4;  // W-tile load map
  float acc[4][4] = {};

  for (int kt = 0; kt < 512; kt += 16) {
    float4 a4 = *(const float4*)&A[(size_t)(m0 + lm) * 512 + kt + lk4];
    float4 w4 = *(const float4*)&W[(size_t)(kt + wk) * 512 + n0 + wn4];
    __syncthreads();                 // previous-iter reads done before overwrite
    As[(lk4 + 0) * 68 + lm] = a4.x;
    As[(lk4 + 1) * 68 + lm] = a4.y;
    As[(lk4 + 2) * 68 + lm] = a4.z;
    As[(lk4 + 3) * 68 + lm] = a4.w;
    *(float4*)&Ws[wk * 68 + wn4] = w4;
    __syncthreads();
    #pragma unroll
    for (int kk = 0; kk < 16; kk++) {
      float4 av = *(const float4*)&As[kk * 68 + 4 * ty];
      float4 wv = *(const float4*)&Ws[kk * 68 + 4 * tx];
      float a[4] = {av.x, av.y, av.z, av.w};
      float w[4] = {wv.x, wv.y, wv.z, wv.w};
      #pragma unroll
      for (int ii = 0; ii < 4; ii++)
        #pragma unroll
        for (int jj = 0; jj < 4; jj++)
          acc[ii][jj] = fmaf(a[ii], w[jj], acc[ii][jj]);
    }
  }
  #pragma unroll
  for (int ii = 0; ii < 4; ii++) {
    float4 o = {acc[ii][0], acc[ii][1], acc[ii][2], acc[ii][3]};
    *(float4*)&C[(size_t)(m0 + 4 * ty + ii) * 512 + n0 + 4 * tx] = o;
  }
}

// ---------------- fused flash attention with table bias --------------------
// grid = (NQ/TQ, NH, B), block = 256
__global__ __launch_bounds__(256) void attn_kernel(
    const float* __restrict__ Q,    // [B*NQ, 512] head-major cols
    const float* __restrict__ K,    // [B*NK, 512]
    const float* __restrict__ V,    // [B*NK, 512]
    const float* __restrict__ qc_g, // [B*NQ, 3]
    const float* __restrict__ kc_g, // [B*NK, 3]
    const float* __restrict__ tbl_g,// [NH][TBL1]
    float* __restrict__ O) {        // [B*NQ, 512]
  __shared__ float qs[TQ * 68];
  __shared__ float ks[TK * 68];
  __shared__ float vs[TK * 68];
  __shared__ float pt[TK * 36];     // P transposed [j][i]
  __shared__ float qcx[TQ], qcy[TQ], qcz[TQ];
  __shared__ float kcx[TK], kcy[TK], kcz[TK];
  __shared__ float sm_m[TQ], sm_l[TQ], sm_al[TQ];
  __shared__ float tbl[TBL1];

  const int t  = threadIdx.x;
  const int qt = blockIdx.x;
  const int h  = blockIdx.y;
  const int b  = blockIdx.z;
  const float scale = 0.125f;   // HD^-0.5

  // stage Q tile (32 rows x 64 cols of this head)
  const float* Qbase = Q + (size_t)(b * NQ + qt * TQ) * 512 + h * HD;
  #pragma unroll
  for (int u = 0; u < 2; u++) {
    int f = 2 * t + u;                 // 512 float4s
    int r = f >> 4, c4 = (f & 15) * 4;
    *(float4*)&qs[r * 68 + c4] = *(const float4*)&Qbase[(size_t)r * 512 + c4];
  }
  if (t < TQ) {
    size_t ci = (size_t)(b * NQ + qt * TQ + t) * 3;
    qcx[t] = qc_g[ci]; qcy[t] = qc_g[ci + 1]; qcz[t] = qc_g[ci + 2];
    sm_m[t] = -INFINITY; sm_l[t] = 0.0f;
  }
  for (int i = t; i < TBL1; i += 256) tbl[i] = tbl_g[h * TBL1 + i];

  const int ti  = t >> 4;      // 0..15 -> rows {2ti, 2ti+1}
  const int tjj = t & 15;      // 0..15 -> cols {2tjj, 2tjj+1} in S phase
  const int i0  = 2 * ti;
  const int j0  = 2 * tjj;
  const int dc  = t & 15;      // PV: d-cols 4dc..4dc+3
  float acc[2][4] = {};

  const float* Kbase = K + (size_t)b * NK * 512 + h * HD;
  const float* Vbase = V + (size_t)b * NK * 512 + h * HD;

  for (int jt = 0; jt < NK / TK; jt++) {
    const int jbase = jt * TK;
    __syncthreads();   // previous PV/bias reads done
    #pragma unroll
    for (int u = 0; u < 2; u++) {
      int f = 2 * t + u;
      int r = f >> 4, c4 = (f & 15) * 4;
      *(float4*)&ks[r * 68 + c4] = *(const float4*)&Kbase[(size_t)(jbase + r) * 512 + c4];
      *(float4*)&vs[r * 68 + c4] = *(const float4*)&Vbase[(size_t)(jbase + r) * 512 + c4];
    }
    if (t < TK) {
      size_t ci = (size_t)(b * NK + jbase + t) * 3;
      kcx[t] = kc_g[ci]; kcy[t] = kc_g[ci + 1]; kcz[t] = kc_g[ci + 2];
    }
    __syncthreads();

    // ---- S = Q K^T (2x2 per thread) ----
    float s00 = 0, s01 = 0, s10 = 0, s11 = 0;
    #pragma unroll
    for (int kk = 0; kk < 16; kk++) {
      float4 qa = *(const float4*)&qs[(i0    ) * 68 + 4 * kk];
      float4 qb = *(const float4*)&qs[(i0 + 1) * 68 + 4 * kk];
      float4 ka = *(const float4*)&ks[(j0    ) * 68 + 4 * kk];
      float4 kb = *(const float4*)&ks[(j0 + 1) * 68 + 4 * kk];
      s00 += qa.x*ka.x + qa.y*ka.y + qa.z*ka.z + qa.w*ka.w;
      s01 += qa.x*kb.x + qa.y*kb.y + qa.z*kb.z + qa.w*kb.w;
      s10 += qb.x*ka.x + qb.y*ka.y + qb.z*ka.z + qb.w*ka.w;
      s11 += qb.x*kb.x + qb.y*kb.y + qb.z*kb.z + qb.w*kb.w;
    }
    // ---- distance bias via table ----
    float sv[2][2] = {{s00, s01}, {s10, s11}};
    #pragma unroll
    for (int ii = 0; ii < 2; ii++) {
      #pragma unroll
      for (int jj = 0; jj < 2; jj++) {
        int i = i0 + ii, j = j0 + jj;
        float dx = qcx[i] - kcx[j], dy = qcy[i] - kcy[j], dz = qcz[i] - kcz[j];
        float d = sqrtf(dx * dx + dy * dy + dz * dz);
        float fi = d * INV_DT;
        int idx = (int)fi; idx = idx < TBLN - 1 ? idx : TBLN - 1;
        float fr = fi - idx;
        float t0 = tbl[idx], t1 = tbl[idx + 1];
        sv[ii][jj] = sv[ii][jj] * scale + t0 + fr * (t1 - t0);
      }
    }
    // ---- online softmax (rows owned by 16 tjj lanes) ----
    float rm0 = fmaxf(sv[0][0], sv[0][1]);
    float rm1 = fmaxf(sv[1][0], sv[1][1]);
    #pragma unroll
    for (int m = 1; m <= 8; m <<= 1) {
      rm0 = fmaxf(rm0, __shfl_xor(rm0, m, 64));
      rm1 = fmaxf(rm1, __shfl_xor(rm1, m, 64));
    }
    float mo0 = sm_m[i0], mo1 = sm_m[i0 + 1];
    float mn0 = fmaxf(mo0, rm0), mn1 = fmaxf(mo1, rm1);
    float p00 = __expf(sv[0][0] - mn0), p01 = __expf(sv[0][1] - mn0);
    float p10 = __expf(sv[1][0] - mn1), p11 = __expf(sv[1][1] - mn1);
    float rs0 = p00 + p01, rs1 = p10 + p11;
    #pragma unroll
    for (int m = 1; m <= 8; m <<= 1) {
      rs0 += __shfl_xor(rs0, m, 64);
      rs1 += __shfl_xor(rs1, m, 64);
    }
    if (tjj == 0) {
      float al0 = __expf(mo0 - mn0), al1 = __expf(mo1 - mn1);
      sm_m[i0] = mn0;  sm_m[i0 + 1] = mn1;
      sm_l[i0]     = sm_l[i0]     * al0 + rs0;
      sm_l[i0 + 1] = sm_l[i0 + 1] * al1 + rs1;
      sm_al[i0] = al0; sm_al[i0 + 1] = al1;
    }
    pt[(j0    ) * 36 + i0    ] = p00;
    pt[(j0 + 1) * 36 + i0    ] = p01;
    pt[(j0    ) * 36 + i0 + 1] = p10;
    pt[(j0 + 1) * 36 + i0 + 1] = p11;
    __syncthreads();

    // ---- PV accumulate: rows {i0,i0+1}, cols 4dc..4dc+3 ----
    float al0 = sm_al[i0], al1 = sm_al[i0 + 1];
    #pragma unroll
    for (int c = 0; c < 4; c++) { acc[0][c] *= al0; acc[1][c] *= al1; }
    #pragma unroll
    for (int j = 0; j < TK; j++) {
      float2 p  = *(const float2*)&pt[j * 36 + i0];
      float4 v4 = *(const float4*)&vs[j * 68 + 4 * dc];
      acc[0][0] = fmaf(p.x, v4.x, acc[0][0]);
      acc[0][1] = fmaf(p.x, v4.y, acc[0][1]);
      acc[0][2] = fmaf(p.x, v4.z, acc[0][2]);
      acc[0][3] = fmaf(p.x, v4.w, acc[0][3]);
      acc[1][0] = fmaf(p.y, v4.x, acc[1][0]);
      acc[1][1] = fmaf(p.y, v4.y, acc[1][1]);
      acc[1][2] = fmaf(p.y, v4.z, acc[1][2]);
      acc[1][3] = fmaf(p.y, v4.w, acc[1][3]);
    }
  }

  // epilogue: normalize and store
  float inv0 = 1.0f / sm_l[i0], inv1 = 1.0f / sm_l[i0 + 1];
  float* Obase = O + (size_t)(b * NQ + qt * TQ) * 512 + h * HD;
  float4 o0 = {acc[0][0] * inv0, acc[0][1] * inv0, acc[0][2] * inv0, acc[0][3] * inv0};
  float4 o1 = {acc[1][0] * inv1, acc[1][1] * inv1, acc[1][2] * inv1, acc[1][3] * inv1};
  *(float4*)&Obase[(size_t)(i0    ) * 512 + 4 * dc] = o0;
  *(float4*)&Obase[(size_t)(i0 + 1) * 512 + 4 * dc] = o1;
}

extern "C" void kernel_launch(void* const* d_in, const int* in_sizes, int n_in,
                              void* d_out, int out_size, void* d_ws, size_t ws_size,
                              hipStream_t stream) {
  const float* q_in      = (const float*)d_in[0];
  const float* kv_in     = (const float*)d_in[1];
  const float* q_coords  = (const float*)d_in[2];
  const float* kv_coords = (const float*)d_in[3];
  const float* Wq        = (const float*)d_in[4];
  const float* Wk        = (const float*)d_in[5];
  const float* Wv        = (const float*)d_in[6];
  const float* Wo        = (const float*)d_in[7];
  const float* W1        = (const float*)d_in[8];
  const float* b1        = (const float*)d_in[9];
  const float* W2        = (const float*)d_in[10];
  const float* b2        = (const float*)d_in[11];
  float* out = (float*)d_out;

  float* ws   = (float*)d_ws;
  float* Q    = ws;                          // 2048*512
  float* K    = Q + (size_t)BB * NQ * 512;   // 4096*512
  float* V    = K + (size_t)BB * NK * 512;   // 4096*512
  float* AO   = V + (size_t)BB * NK * 512;   // 2048*512
  float* TBLG = AO + (size_t)BB * NQ * 512;  // 8*2049

  bias_table_kernel<<<(TBL1 + 255) / 256, 256, 0, stream>>>(W1, b1, W2, b2, TBLG);
  gemm512<<<dim3((BB * NQ) / 64, 8), 256, 0, stream>>>(q_in, Wq, Q);
  gemm512<<<dim3((BB * NK) / 64, 8), 256, 0, stream>>>(kv_in, Wk, K);
  gemm512<<<dim3((BB * NK) / 64, 8), 256, 0, stream>>>(kv_in, Wv, V);
  attn_kernel<<<dim3(NQ / TQ, NH, BB), 256, 0, stream>>>(Q, K, V, q_coords, kv_coords, TBLG, AO);
  gemm512<<<dim3((BB * NQ) / 64, 8), 256, 0, stream>>>(AO, Wo, out);
}

// Round 2
// 220.806 us; speedup vs baseline: 2.2383x; 2.2383x over previous
//
#include <hip/hip_runtime.h>
#include <hip/hip_bf16.h>
#include <hip/hip_fp16.h>
#include <math.h>

typedef short bf16x8 __attribute__((ext_vector_type(8)));
typedef float f32x4 __attribute__((ext_vector_type(4)));
typedef unsigned short u16;
typedef unsigned int u32;

#define NH 8
#define HD 64
#define BB 2
#define NQ 1024
#define NK 2048

#define MFMA16(a, b, c) __builtin_amdgcn_mfma_f32_16x16x32_bf16(a, b, c, 0, 0, 0)

static __device__ __forceinline__ u16 f2us(float x) {
  union { __hip_bfloat16 b; u16 u; } cv;
  cv.b = __float2bfloat16(x);
  return cv.u;
}

// ---------------- fp32 -> bf16 cast, 4 elems/thread ------------------------
__global__ __launch_bounds__(256) void cast_kernel(const float* __restrict__ x,
                                                   u16* __restrict__ y, int n4) {
  int i = blockIdx.x * 256 + threadIdx.x;
  if (i >= n4) return;
  float4 v = *(const float4*)(x + (size_t)i * 4);
  uint2 o;
  o.x = f2us(v.x) | ((u32)f2us(v.y) << 16);
  o.y = f2us(v.z) | ((u32)f2us(v.w) << 16);
  *(uint2*)(y + (size_t)i * 4) = o;
}

// ---------------- transpose+cast: Wt[n][k] = bf16(W[k][n]) -----------------
__global__ __launch_bounds__(256) void tcast_kernel(const float* __restrict__ W,
                                                    u16* __restrict__ Wt) {
  __shared__ u16 tile[64][65];
  const int t = threadIdx.x;
  const int k0 = blockIdx.x * 64, n0 = blockIdx.y * 64;
  const int r = t >> 4, c4 = (t & 15) * 4;
  #pragma unroll
  for (int p = 0; p < 4; p++) {
    int row = p * 16 + r;
    float4 v = *(const float4*)&W[(size_t)(k0 + row) * 512 + n0 + c4];
    tile[row][c4 + 0] = f2us(v.x);
    tile[row][c4 + 1] = f2us(v.y);
    tile[row][c4 + 2] = f2us(v.z);
    tile[row][c4 + 3] = f2us(v.w);
  }
  __syncthreads();
  #pragma unroll
  for (int p = 0; p < 4; p++) {
    int n = p * 16 + r;
    u16 u0 = tile[c4 + 0][n], u1 = tile[c4 + 1][n];
    u16 u2 = tile[c4 + 2][n], u3 = tile[c4 + 3][n];
    uint2 o;
    o.x = u0 | ((u32)u1 << 16);
    o.y = u2 | ((u32)u3 << 16);
    *(uint2*)&Wt[(size_t)(n0 + n) * 512 + k0 + c4] = o;
  }
}

// ---------------- bias table: per head, packed half2(value, delta) ---------
__global__ __launch_bounds__(256) void table_kernel(const float* __restrict__ W1,
                                                    const float* __restrict__ b1,
                                                    const float* __restrict__ W2,
                                                    const float* __restrict__ b2,
                                                    u32* __restrict__ tblp) {
  int k = blockIdx.x * 256 + threadIdx.x;
  if (k >= 2048) return;
  float d0 = (float)k * (1.0f / 128.0f);
  float d1 = (float)(k + 1) * (1.0f / 128.0f);
  float a0[8], a1[8];
  #pragma unroll
  for (int h = 0; h < 8; h++) { a0[h] = b2[h]; a1[h] = b2[h]; }
  for (int r = 0; r < 64; r++) {
    float w = W1[r], bb = b1[r];
    float x0 = d0 * w + bb, x1 = d1 * w + bb;
    float s0 = x0 / (1.0f + expf(-x0));
    float s1 = x1 / (1.0f + expf(-x1));
    #pragma unroll
    for (int h = 0; h < 8; h++) {
      a0[h] += s0 * W2[r * 8 + h];
      a1[h] += s1 * W2[r * 8 + h];
    }
  }
  #pragma unroll
  for (int h = 0; h < 8; h++) {
    __half lo = __float2half(a0[h]);
    __half dl = __float2half(a1[h] - a0[h]);
    tblp[h * 2048 + k] = (u32)__half_as_ushort(lo) | ((u32)__half_as_ushort(dl) << 16);
  }
}

// ---------------- bf16 MFMA GEMM: C[M,512] = A[M,512] @ Bt[n][k]^T ---------
// MODE 0: bf16 row-major out; MODE 1: fp32 row-major out; MODE 2: Vt out
template <int MODE>
__global__ __launch_bounds__(256) void gemm_mfma(const u16* __restrict__ A,
                                                 const u16* __restrict__ Bt,
                                                 void* __restrict__ Cv) {
  __shared__ u16 As[64 * 40];
  __shared__ u16 Bs[64 * 40];
  const int t = threadIdx.x;
  const int w = t >> 6, l = t & 63, g = l >> 4, li = l & 15;
  const int m0 = blockIdx.x * 64, n0 = blockIdx.y * 64;
  const int ms = (w & 1) * 32, ns = (w >> 1) * 32;
  const int lrow = t >> 2, lc8 = (t & 3) * 8;
  f32x4 acc[2][2] = {};
  for (int kt = 0; kt < 512; kt += 32) {
    bf16x8 av = *(const bf16x8*)&A[(size_t)(m0 + lrow) * 512 + kt + lc8];
    bf16x8 bv = *(const bf16x8*)&Bt[(size_t)(n0 + lrow) * 512 + kt + lc8];
    __syncthreads();
    *(bf16x8*)&As[lrow * 40 + lc8] = av;
    *(bf16x8*)&Bs[lrow * 40 + lc8] = bv;
    __syncthreads();
    bf16x8 a0 = *(const bf16x8*)&As[(ms + li) * 40 + g * 8];
    bf16x8 a1 = *(const bf16x8*)&As[(ms + 16 + li) * 40 + g * 8];
    bf16x8 b0 = *(const bf16x8*)&Bs[(ns + li) * 40 + g * 8];
    bf16x8 b1 = *(const bf16x8*)&Bs[(ns + 16 + li) * 40 + g * 8];
    acc[0][0] = MFMA16(a0, b0, acc[0][0]);
    acc[0][1] = MFMA16(a0, b1, acc[0][1]);
    acc[1][0] = MFMA16(a1, b0, acc[1][0]);
    acc[1][1] = MFMA16(a1, b1, acc[1][1]);
  }
  #pragma unroll
  for (int mi = 0; mi < 2; mi++) {
    #pragma unroll
    for (int ni = 0; ni < 2; ni++) {
      f32x4 v = acc[mi][ni];
      int row = m0 + ms + mi * 16 + 4 * g;
      int col = n0 + ns + ni * 16 + li;
      if (MODE == 0) {
        u16* C = (u16*)Cv;
        #pragma unroll
        for (int r = 0; r < 4; r++) C[(size_t)(row + r) * 512 + col] = f2us(v[r]);
      } else if (MODE == 1) {
        float* C = (float*)Cv;
        #pragma unroll
        for (int r = 0; r < 4; r++) C[(size_t)(row + r) * 512 + col] = v[r];
      } else {
        u16* C = (u16*)Cv;
        int bb = row >> 11, j = row & 2047;
        int hh = col >> 6, d = col & 63;
        uint2 o;
        o.x = f2us(v[0]) | ((u32)f2us(v[1]) << 16);
        o.y = f2us(v[2]) | ((u32)f2us(v[3]) << 16);
        *(uint2*)&C[((size_t)((bb * 8 + hh) * 64 + d)) * 2048 + j] = o;
      }
    }
  }
}

// ---------------- fused MFMA flash attention with table bias ---------------
// grid (16, 8, 2) = (qtile64, head, batch); block 256 = 4 waves, wave = 16 q-rows
__global__ __launch_bounds__(256) void attn_kernel(
    const u16* __restrict__ Qb, const u16* __restrict__ Kb,
    const u16* __restrict__ Vt, const float* __restrict__ qc,
    const float* __restrict__ kc, const u32* __restrict__ tblp,
    u16* __restrict__ AOb) {
  __shared__ u16 Kl[64 * 72];    // K tile  [j][d], pad 72
  __shared__ u16 Vtl[64 * 72];   // Vt tile [d][j], pad 72
  __shared__ u16 Pl[64 * 72];    // P per wave [i][j], pad 72
  __shared__ u16 keb[512 * 8];   // aug K coord vecs (chunked)
  __shared__ u32 tblS[2048];     // packed half2 bias table for this head

  const int t = threadIdx.x;
  const int w = t >> 6, l = t & 63, g = l >> 4, li = l & 15;
  const int qt = blockIdx.x, h = blockIdx.y, b = blockIdx.z;

  for (int k = t; k < 2048; k += 256) tblS[k] = tblp[h * 2048 + k];

  const int qrow = qt * 64 + w * 16 + li;
  const size_t qg = (size_t)b * NQ + qrow;
  // Q frags live in registers for the whole kernel (B-operand: n=li, k contig)
  bf16x8 qf0 = *(const bf16x8*)&Qb[qg * 512 + h * 64 + g * 8];
  bf16x8 qf1 = *(const bf16x8*)&Qb[qg * 512 + h * 64 + 32 + g * 8];
  float qx = qc[qg * 3 + 0], qy = qc[qg * 3 + 1], qz = qc[qg * 3 + 2];
  bf16x8 qe = {};
  if (g == 0) {
    qe[0] = (short)f2us(qx);
    qe[1] = (short)f2us(qy);
    qe[2] = (short)f2us(qz);
    qe[3] = (short)f2us(qx * qx + qy * qy + qz * qz);
    qe[4] = (short)f2us(1.0f);
  }

  f32x4 oacc[4] = {};
  float mold = -INFINITY, lsum = 0.0f;

  const u16* Kg = Kb + (size_t)b * NK * 512 + h * 64;
  const u16* Vg = Vt + (size_t)((b * 8 + h) * 64) * 2048;

  for (int ch = 0; ch < 4; ch++) {
    const int cbase = ch * 512;
    // build augmented K-coord vectors for this 512-j chunk
    for (int jj = t; jj < 512; jj += 256) {
      size_t kr = (size_t)b * NK + cbase + jj;
      float kx = kc[kr * 3], ky = kc[kr * 3 + 1], kz = kc[kr * 3 + 2];
      u16* p = &keb[jj * 8];
      p[0] = f2us(-2.0f * kx);
      p[1] = f2us(-2.0f * ky);
      p[2] = f2us(-2.0f * kz);
      p[3] = f2us(1.0f);
      p[4] = f2us(kx * kx + ky * ky + kz * kz);
      p[5] = 0; p[6] = 0; p[7] = 0;
    }
    for (int it = 0; it < 8; it++) {
      const int jbase = cbase + it * 64;
      #pragma unroll
      for (int pp = 0; pp < 2; pp++) {
        int f = pp * 256 + t;
        int row = f >> 3, c8 = (f & 7) * 8;
        *(bf16x8*)&Kl[row * 72 + c8] =
            *(const bf16x8*)&Kg[(size_t)(jbase + row) * 512 + c8];
        *(bf16x8*)&Vtl[row * 72 + c8] =
            *(const bf16x8*)&Vg[(size_t)row * 2048 + jbase + c8];
      }
      __syncthreads();

      // S^T = K·Q^T  (D[j][i]) and d² via aug MFMA, same C layout
      f32x4 sac[4], dac[4];
      #pragma unroll
      for (int j4 = 0; j4 < 4; j4++) {
        bf16x8 ka0 = *(const bf16x8*)&Kl[(j4 * 16 + li) * 72 + g * 8];
        bf16x8 ka1 = *(const bf16x8*)&Kl[(j4 * 16 + li) * 72 + 32 + g * 8];
        f32x4 z = {};
        f32x4 s = MFMA16(ka0, qf0, z);
        sac[j4] = MFMA16(ka1, qf1, s);
        bf16x8 ke = {};
        if (g == 0) ke = *(const bf16x8*)&keb[(it * 64 + j4 * 16 + li) * 8];
        dac[j4] = MFMA16(ke, qe, z);
      }

      // bias + logits; lane owns row i=li, j = j4*16 + 4g + r
      float lg[16];
      float tmax = -INFINITY;
      #pragma unroll
      for (int j4 = 0; j4 < 4; j4++) {
        #pragma unroll
        for (int r = 0; r < 4; r++) {
          float d2 = fmaxf(dac[j4][r], 0.0f);
          float d = sqrtf(d2);
          float fi = d * 128.0f;
          int idx = (int)fi;
          idx = idx < 2047 ? idx : 2047;
          float fr = fi - (float)idx;
          union { u32 u; __half2 h2; } uu;
          uu.u = tblS[idx];
          float bias = __low2float(uu.h2) + fr * __high2float(uu.h2);
          float L = fmaf(sac[j4][r], 0.125f, bias);
          lg[j4 * 4 + r] = L;
          tmax = fmaxf(tmax, L);
        }
      }
      tmax = fmaxf(tmax, __shfl_xor(tmax, 16));
      tmax = fmaxf(tmax, __shfl_xor(tmax, 32));
      float mnew = fmaxf(mold, tmax);
      float alpha = __expf(mold - mnew);
      float rsum = 0.0f;
      #pragma unroll
      for (int j4 = 0; j4 < 4; j4++) {
        float p0 = __expf(lg[j4 * 4 + 0] - mnew);
        float p1 = __expf(lg[j4 * 4 + 1] - mnew);
        float p2 = __expf(lg[j4 * 4 + 2] - mnew);
        float p3 = __expf(lg[j4 * 4 + 3] - mnew);
        rsum += (p0 + p1) + (p2 + p3);
        uint2 pv;
        pv.x = f2us(p0) | ((u32)f2us(p1) << 16);
        pv.y = f2us(p2) | ((u32)f2us(p3) << 16);
        *(uint2*)&Pl[(w * 16 + li) * 72 + j4 * 16 + g * 4] = pv;
      }
      rsum += __shfl_xor(rsum, 16);
      rsum += __shfl_xor(rsum, 32);
      lsum = lsum * alpha + rsum;
      mold = mnew;

      // rescale O-acc (rows 4g+r need alpha of those rows -> shuffle)
      float a0 = __shfl(alpha, 4 * g + 0);
      float a1 = __shfl(alpha, 4 * g + 1);
      float a2 = __shfl(alpha, 4 * g + 2);
      float a3 = __shfl(alpha, 4 * g + 3);
      #pragma unroll
      for (int dt = 0; dt < 4; dt++) {
        oacc[dt][0] *= a0; oacc[dt][1] *= a1;
        oacc[dt][2] *= a2; oacc[dt][3] *= a3;
      }
      // PV: A = P (m=i, k=j), B = Vt (k=j, n=d); intra-wave LDS roundtrip
      bf16x8 pf0 = *(const bf16x8*)&Pl[(w * 16 + li) * 72 + g * 8];
      bf16x8 pf1 = *(const bf16x8*)&Pl[(w * 16 + li) * 72 + 32 + g * 8];
      #pragma unroll
      for (int dt = 0; dt < 4; dt++) {
        bf16x8 v0 = *(const bf16x8*)&Vtl[(dt * 16 + li) * 72 + g * 8];
        bf16x8 v1 = *(const bf16x8*)&Vtl[(dt * 16 + li) * 72 + 32 + g * 8];
        oacc[dt] = MFMA16(pf0, v0, oacc[dt]);
        oacc[dt] = MFMA16(pf1, v1, oacc[dt]);
      }
      __syncthreads();
    }
  }

  float inv = 1.0f / lsum;
  float i0 = __shfl(inv, 4 * g + 0), i1 = __shfl(inv, 4 * g + 1);
  float i2 = __shfl(inv, 4 * g + 2), i3 = __shfl(inv, 4 * g + 3);
  u16* Ob = AOb + ((size_t)b * NQ + qt * 64 + w * 16) * 512 + h * 64;
  #pragma unroll
  for (int dt = 0; dt < 4; dt++) {
    Ob[(size_t)(4 * g + 0) * 512 + dt * 16 + li] = f2us(oacc[dt][0] * i0);
    Ob[(size_t)(4 * g + 1) * 512 + dt * 16 + li] = f2us(oacc[dt][1] * i1);
    Ob[(size_t)(4 * g + 2) * 512 + dt * 16 + li] = f2us(oacc[dt][2] * i2);
    Ob[(size_t)(4 * g + 3) * 512 + dt * 16 + li] = f2us(oacc[dt][3] * i3);
  }
}

extern "C" void kernel_launch(void* const* d_in, const int* in_sizes, int n_in,
                              void* d_out, int out_size, void* d_ws, size_t ws_size,
                              hipStream_t stream) {
  const float* q_in      = (const float*)d_in[0];
  const float* kv_in     = (const float*)d_in[1];
  const float* q_coords  = (const float*)d_in[2];
  const float* kv_coords = (const float*)d_in[3];
  const float* Wq        = (const float*)d_in[4];
  const float* Wk        = (const float*)d_in[5];
  const float* Wv        = (const float*)d_in[6];
  const float* Wo        = (const float*)d_in[7];
  const float* W1        = (const float*)d_in[8];
  const float* b1        = (const float*)d_in[9];
  const float* W2        = (const float*)d_in[10];
  const float* b2        = (const float*)d_in[11];

  char* p = (char*)d_ws;
  u16* qb   = (u16*)p; p += (size_t)2048 * 512 * 2;
  u16* kvb  = (u16*)p; p += (size_t)4096 * 512 * 2;
  u16* Wqt  = (u16*)p; p += (size_t)512 * 512 * 2;
  u16* Wkt  = (u16*)p; p += (size_t)512 * 512 * 2;
  u16* Wvt  = (u16*)p; p += (size_t)512 * 512 * 2;
  u16* Wot  = (u16*)p; p += (size_t)512 * 512 * 2;
  u16* Qp   = (u16*)p; p += (size_t)2048 * 512 * 2;
  u16* Kp   = (u16*)p; p += (size_t)4096 * 512 * 2;
  u16* Vtp  = (u16*)p; p += (size_t)4096 * 512 * 2;
  u16* AOb  = (u16*)p; p += (size_t)2048 * 512 * 2;
  u32* tblp = (u32*)p; p += (size_t)8 * 2048 * 4;

  cast_kernel<<<1024, 256, 0, stream>>>(q_in, qb, 262144);
  cast_kernel<<<2048, 256, 0, stream>>>(kv_in, kvb, 524288);
  tcast_kernel<<<dim3(8, 8), 256, 0, stream>>>(Wq, Wqt);
  tcast_kernel<<<dim3(8, 8), 256, 0, stream>>>(Wk, Wkt);
  tcast_kernel<<<dim3(8, 8), 256, 0, stream>>>(Wv, Wvt);
  tcast_kernel<<<dim3(8, 8), 256, 0, stream>>>(Wo, Wot);
  table_kernel<<<8, 256, 0, stream>>>(W1, b1, W2, b2, tblp);

  gemm_mfma<0><<<dim3(32, 8), 256, 0, stream>>>(qb, Wqt, Qp);
  gemm_mfma<0><<<dim3(64, 8), 256, 0, stream>>>(kvb, Wkt, Kp);
  gemm_mfma<2><<<dim3(64, 8), 256, 0, stream>>>(kvb, Wvt, Vtp);
  attn_kernel<<<dim3(16, 8, 2), 256, 0, stream>>>(Qp, Kp, Vtp, q_coords,
                                                  kv_coords, tblp, AOb);
  gemm_mfma<1><<<dim3(32, 8), 256, 0, stream>>>(AOb, Wot, d_out);
}

// Round 3
// 165.336 us; speedup vs baseline: 2.9893x; 1.3355x over previous
//
#include <hip/hip_runtime.h>
#include <hip/hip_bf16.h>
#include <hip/hip_fp16.h>
#include <math.h>

typedef short bf16x8 __attribute__((ext_vector_type(8)));
typedef float f32x4 __attribute__((ext_vector_type(4)));
typedef unsigned short u16;
typedef unsigned int u32;

#define NH 8
#define BB 2
#define NQ 1024
#define NK 2048
#define M2CONST 6.4921250f   // 4.5 * log2(e)
#define SC2 0.18033688f      // 0.125 * log2(e)

#define MFMA16(a, b, c) __builtin_amdgcn_mfma_f32_16x16x32_bf16(a, b, c, 0, 0, 0)

static __device__ __forceinline__ u16 f2us(float x) {
  union { __hip_bfloat16 b; u16 u; } cv;
  cv.b = __float2bfloat16(x);
  return cv.u;
}

// ---------------- fused fp32 -> bf16 cast for q_in and kv_in ---------------
__global__ __launch_bounds__(256) void castall_kernel(const float* __restrict__ q_in,
                                                      const float* __restrict__ kv_in,
                                                      u16* __restrict__ qb,
                                                      u16* __restrict__ kvb) {
  int i = blockIdx.x * 256 + threadIdx.x;
  const float* src; u16* dst; int idx;
  if (i < 262144) { src = q_in; dst = qb; idx = i; }
  else            { src = kv_in; dst = kvb; idx = i - 262144; }
  float4 v = *(const float4*)(src + (size_t)idx * 4);
  uint2 o;
  o.x = f2us(v.x) | ((u32)f2us(v.y) << 16);
  o.y = f2us(v.z) | ((u32)f2us(v.w) << 16);
  *(uint2*)(dst + (size_t)idx * 4) = o;
}

// ---------------- 4-way fused transpose+cast: Wt[n][k] = bf16(W[k][n]) -----
__global__ __launch_bounds__(256) void tcast4_kernel(
    const float* __restrict__ Wq, const float* __restrict__ Wk,
    const float* __restrict__ Wv, const float* __restrict__ Wo,
    u16* __restrict__ Tq, u16* __restrict__ Tk,
    u16* __restrict__ Tv, u16* __restrict__ To) {
  __shared__ u16 tile[64][65];
  const float* W; u16* Wt;
  switch (blockIdx.z) {
    case 0: W = Wq; Wt = Tq; break;
    case 1: W = Wk; Wt = Tk; break;
    case 2: W = Wv; Wt = Tv; break;
    default: W = Wo; Wt = To; break;
  }
  const int t = threadIdx.x;
  const int k0 = blockIdx.x * 64, n0 = blockIdx.y * 64;
  const int r = t >> 4, c4 = (t & 15) * 4;
  #pragma unroll
  for (int p = 0; p < 4; p++) {
    int row = p * 16 + r;
    float4 v = *(const float4*)&W[(size_t)(k0 + row) * 512 + n0 + c4];
    tile[row][c4 + 0] = f2us(v.x);
    tile[row][c4 + 1] = f2us(v.y);
    tile[row][c4 + 2] = f2us(v.z);
    tile[row][c4 + 3] = f2us(v.w);
  }
  __syncthreads();
  #pragma unroll
  for (int p = 0; p < 4; p++) {
    int n = p * 16 + r;
    u16 u0 = tile[c4 + 0][n], u1 = tile[c4 + 1][n];
    u16 u2 = tile[c4 + 2][n], u3 = tile[c4 + 3][n];
    uint2 o;
    o.x = u0 | ((u32)u1 << 16);
    o.y = u2 | ((u32)u3 << 16);
    *(uint2*)&Wt[(size_t)(n0 + n) * 512 + k0 + c4] = o;
  }
}

// ------ table (w = exp(f(d)) vs d^2, packed half2(w, dw)) + keg build ------
__global__ __launch_bounds__(256) void tablekeg_kernel(
    const float* __restrict__ W1, const float* __restrict__ b1,
    const float* __restrict__ W2, const float* __restrict__ b2,
    u32* __restrict__ tblp, const float* __restrict__ kc,
    u16* __restrict__ keg) {
  const int blk = blockIdx.x, t = threadIdx.x;
  if (blk < 8) {
    int k = blk * 256 + t;   // 0..2047, u = d^2 = k/32
    float d0 = sqrtf((float)k * (1.0f / 32.0f));
    float d1 = sqrtf((float)(k + 1) * (1.0f / 32.0f));
    float a0[8], a1[8];
    #pragma unroll
    for (int h = 0; h < 8; h++) { a0[h] = b2[h]; a1[h] = b2[h]; }
    for (int r = 0; r < 64; r++) {
      float w = W1[r], bb = b1[r];
      float x0 = d0 * w + bb, x1 = d1 * w + bb;
      float s0 = x0 / (1.0f + expf(-x0));
      float s1 = x1 / (1.0f + expf(-x1));
      #pragma unroll
      for (int h = 0; h < 8; h++) {
        a0[h] += s0 * W2[r * 8 + h];
        a1[h] += s1 * W2[r * 8 + h];
      }
    }
    #pragma unroll
    for (int h = 0; h < 8; h++) {
      float w0 = expf(a0[h]), w1 = expf(a1[h]);
      __half lo = __float2half(w0);
      __half dl = __float2half(w1 - w0);
      tblp[h * 2048 + k] = (u32)__half_as_ushort(lo) | ((u32)__half_as_ushort(dl) << 16);
    }
  } else {
    int r = (blk - 8) * 256 + t;   // 0..4095 (B*NK rows)
    float kx = kc[(size_t)r * 3], ky = kc[(size_t)r * 3 + 1], kz = kc[(size_t)r * 3 + 2];
    uint4 o;
    o.x = f2us(-2.0f * kx) | ((u32)f2us(-2.0f * ky) << 16);
    o.y = f2us(-2.0f * kz) | ((u32)f2us(1.0f) << 16);
    o.z = (u32)f2us(kx * kx + ky * ky + kz * kz);
    o.w = 0;
    *(uint4*)&keg[(size_t)r * 8] = o;
  }
}

// ---------------- bf16 MFMA GEMM, BK=64: C[M,512] = A @ Bt^T ---------------
// MODE 0: bf16 row-major out; MODE 1: fp32 row-major out
template <int TM, int MODE>
__global__ __launch_bounds__(256) void gemm_mfma(const u16* __restrict__ A,
                                                 const u16* __restrict__ Bt,
                                                 void* __restrict__ Cv) {
  __shared__ u16 As[TM * 72];
  __shared__ u16 Bs[64 * 72];
  const int t = threadIdx.x;
  const int w = t >> 6, l = t & 63, g = l >> 4, li = l & 15;
  const int m0 = blockIdx.x * TM, n0 = blockIdx.y * 64;
  const int ms = (TM == 64) ? (w & 1) * 32 : (w & 1) * 16;
  const int ns = (w >> 1) * 32;
  constexpr int MI = (TM == 64) ? 2 : 1;
  f32x4 acc[MI][2] = {};

  for (int kt = 0; kt < 512; kt += 64) {
    bf16x8 av[TM / 32], bv[2];
    #pragma unroll
    for (int p = 0; p < TM / 32; p++) {
      int f = p * 256 + t, r = f >> 3, c8 = (f & 7) * 8;
      av[p] = *(const bf16x8*)&A[(size_t)(m0 + r) * 512 + kt + c8];
    }
    #pragma unroll
    for (int p = 0; p < 2; p++) {
      int f = p * 256 + t, r = f >> 3, c8 = (f & 7) * 8;
      bv[p] = *(const bf16x8*)&Bt[(size_t)(n0 + r) * 512 + kt + c8];
    }
    __syncthreads();
    #pragma unroll
    for (int p = 0; p < TM / 32; p++) {
      int f = p * 256 + t, r = f >> 3, c8 = (f & 7) * 8;
      *(bf16x8*)&As[r * 72 + c8] = av[p];
    }
    #pragma unroll
    for (int p = 0; p < 2; p++) {
      int f = p * 256 + t, r = f >> 3, c8 = (f & 7) * 8;
      *(bf16x8*)&Bs[r * 72 + c8] = bv[p];
    }
    __syncthreads();
    #pragma unroll
    for (int ks = 0; ks < 2; ks++) {
      bf16x8 af[MI], bfr[2];
      af[0] = *(const bf16x8*)&As[(ms + li) * 72 + ks * 32 + g * 8];
      if constexpr (MI == 2)
        af[1] = *(const bf16x8*)&As[(ms + 16 + li) * 72 + ks * 32 + g * 8];
      bfr[0] = *(const bf16x8*)&Bs[(ns + li) * 72 + ks * 32 + g * 8];
      bfr[1] = *(const bf16x8*)&Bs[(ns + 16 + li) * 72 + ks * 32 + g * 8];
      #pragma unroll
      for (int mi = 0; mi < MI; mi++)
        #pragma unroll
        for (int ni = 0; ni < 2; ni++)
          acc[mi][ni] = MFMA16(af[mi], bfr[ni], acc[mi][ni]);
    }
  }
  #pragma unroll
  for (int mi = 0; mi < MI; mi++) {
    #pragma unroll
    for (int ni = 0; ni < 2; ni++) {
      f32x4 v = acc[mi][ni];
      int row = m0 + ms + mi * 16 + 4 * g;
      int col = n0 + ns + ni * 16 + li;
      if (MODE == 0) {
        u16* C = (u16*)Cv;
        #pragma unroll
        for (int r = 0; r < 4; r++) C[(size_t)(row + r) * 512 + col] = f2us(v[r]);
      } else {
        float* C = (float*)Cv;
        #pragma unroll
        for (int r = 0; r < 4; r++) C[(size_t)(row + r) * 512 + col] = v[r];
      }
    }
  }
}

// ---------------- fused K+V projection (shared A-tiles), BK=64 -------------
__global__ __launch_bounds__(256) void gemm_kv(const u16* __restrict__ A,
                                               const u16* __restrict__ BtK,
                                               const u16* __restrict__ BtV,
                                               u16* __restrict__ Kp,
                                               u16* __restrict__ Vtp) {
  __shared__ u16 As[64 * 72];
  __shared__ u16 BsK[64 * 72];
  __shared__ u16 BsV[64 * 72];
  const int t = threadIdx.x;
  const int w = t >> 6, l = t & 63, g = l >> 4, li = l & 15;
  const int m0 = blockIdx.x * 64, n0 = blockIdx.y * 64;
  const int ms = (w & 1) * 32, ns = (w >> 1) * 32;
  f32x4 aK[2][2] = {}, aV[2][2] = {};

  for (int kt = 0; kt < 512; kt += 64) {
    bf16x8 av[2], bk[2], bvv[2];
    #pragma unroll
    for (int p = 0; p < 2; p++) {
      int f = p * 256 + t, r = f >> 3, c8 = (f & 7) * 8;
      av[p]  = *(const bf16x8*)&A[(size_t)(m0 + r) * 512 + kt + c8];
      bk[p]  = *(const bf16x8*)&BtK[(size_t)(n0 + r) * 512 + kt + c8];
      bvv[p] = *(const bf16x8*)&BtV[(size_t)(n0 + r) * 512 + kt + c8];
    }
    __syncthreads();
    #pragma unroll
    for (int p = 0; p < 2; p++) {
      int f = p * 256 + t, r = f >> 3, c8 = (f & 7) * 8;
      *(bf16x8*)&As[r * 72 + c8] = av[p];
      *(bf16x8*)&BsK[r * 72 + c8] = bk[p];
      *(bf16x8*)&BsV[r * 72 + c8] = bvv[p];
    }
    __syncthreads();
    #pragma unroll
    for (int ks = 0; ks < 2; ks++) {
      bf16x8 a0 = *(const bf16x8*)&As[(ms + li) * 72 + ks * 32 + g * 8];
      bf16x8 a1 = *(const bf16x8*)&As[(ms + 16 + li) * 72 + ks * 32 + g * 8];
      bf16x8 k0 = *(const bf16x8*)&BsK[(ns + li) * 72 + ks * 32 + g * 8];
      bf16x8 k1 = *(const bf16x8*)&BsK[(ns + 16 + li) * 72 + ks * 32 + g * 8];
      bf16x8 v0 = *(const bf16x8*)&BsV[(ns + li) * 72 + ks * 32 + g * 8];
      bf16x8 v1 = *(const bf16x8*)&BsV[(ns + 16 + li) * 72 + ks * 32 + g * 8];
      aK[0][0] = MFMA16(a0, k0, aK[0][0]);
      aK[0][1] = MFMA16(a0, k1, aK[0][1]);
      aK[1][0] = MFMA16(a1, k0, aK[1][0]);
      aK[1][1] = MFMA16(a1, k1, aK[1][1]);
      aV[0][0] = MFMA16(a0, v0, aV[0][0]);
      aV[0][1] = MFMA16(a0, v1, aV[0][1]);
      aV[1][0] = MFMA16(a1, v0, aV[1][0]);
      aV[1][1] = MFMA16(a1, v1, aV[1][1]);
    }
  }
  #pragma unroll
  for (int mi = 0; mi < 2; mi++) {
    #pragma unroll
    for (int ni = 0; ni < 2; ni++) {
      int row = m0 + ms + mi * 16 + 4 * g;
      int col = n0 + ns + ni * 16 + li;
      f32x4 vk = aK[mi][ni];
      #pragma unroll
      for (int r = 0; r < 4; r++) Kp[(size_t)(row + r) * 512 + col] = f2us(vk[r]);
      f32x4 vv = aV[mi][ni];
      int bb = row >> 11, j = row & 2047;
      int hh = col >> 6, d = col & 63;
      uint2 o;
      o.x = f2us(vv[0]) | ((u32)f2us(vv[1]) << 16);
      o.y = f2us(vv[2]) | ((u32)f2us(vv[3]) << 16);
      *(uint2*)&Vtp[((size_t)((bb * 8 + hh) * 64 + d)) * 2048 + j] = o;
    }
  }
}

// -------- fixed-max flash attention, split-K x4, d^2-indexed exp table -----
// grid (64, 8, 2): x = qt*4 + split; 4 waves/block, wave = 16 q-rows
__global__ __launch_bounds__(256, 4) void attn_kernel(
    const u16* __restrict__ Qb, const u16* __restrict__ Kb,
    const u16* __restrict__ Vt, const float* __restrict__ qc,
    const u16* __restrict__ keg, const u32* __restrict__ tblp,
    float* __restrict__ Op, float* __restrict__ Lp) {
  __shared__ u16 Kl[64 * 72];
  __shared__ u16 Vtl[64 * 72];
  __shared__ u16 Pl[64 * 72];
  __shared__ u32 tblS[2048];

  const int t = threadIdx.x;
  const int w = t >> 6, l = t & 63, g = l >> 4, li = l & 15;
  const int qt = blockIdx.x >> 2, sidx = blockIdx.x & 3;
  const int h = blockIdx.y, b = blockIdx.z;

  for (int k = t; k < 2048; k += 256) tblS[k] = tblp[h * 2048 + k];

  const int qrow = qt * 64 + w * 16 + li;
  const size_t qg = (size_t)b * NQ + qrow;
  bf16x8 qf0 = *(const bf16x8*)&Qb[qg * 512 + h * 64 + g * 8];
  bf16x8 qf1 = *(const bf16x8*)&Qb[qg * 512 + h * 64 + 32 + g * 8];
  float qx = qc[qg * 3], qy = qc[qg * 3 + 1], qz = qc[qg * 3 + 2];
  bf16x8 qe = {};
  if (g == 0) {
    qe[0] = (short)f2us(qx);
    qe[1] = (short)f2us(qy);
    qe[2] = (short)f2us(qz);
    qe[3] = (short)f2us(qx * qx + qy * qy + qz * qz);
    qe[4] = (short)f2us(1.0f);
  }

  f32x4 oacc[4] = {};
  float lacc = 0.0f;

  const u16* Kg = Kb + (size_t)b * NK * 512 + h * 64;
  const u16* Vg = Vt + (size_t)((b * 8 + h) * 64) * 2048;
  const u16* keg_b = keg + (size_t)b * NK * 8;

  for (int it = 0; it < 8; it++) {
    const int jbase = sidx * 512 + it * 64;
    __syncthreads();
    #pragma unroll
    for (int pp = 0; pp < 2; pp++) {
      int f = pp * 256 + t, row = f >> 3, c8 = (f & 7) * 8;
      *(bf16x8*)&Kl[row * 72 + c8] =
          *(const bf16x8*)&Kg[(size_t)(jbase + row) * 512 + c8];
      *(bf16x8*)&Vtl[row * 72 + c8] =
          *(const bf16x8*)&Vg[(size_t)row * 2048 + jbase + c8];
    }
    __syncthreads();

    // S^T = K Q^T and d^2 via augmented MFMA (C layout: col=i=li, row=j=4g+r)
    f32x4 sac[4], dac[4];
    #pragma unroll
    for (int j4 = 0; j4 < 4; j4++) {
      bf16x8 ka0 = *(const bf16x8*)&Kl[(j4 * 16 + li) * 72 + g * 8];
      bf16x8 ka1 = *(const bf16x8*)&Kl[(j4 * 16 + li) * 72 + 32 + g * 8];
      f32x4 z = {};
      f32x4 s0 = MFMA16(ka0, qf0, z);
      sac[j4] = MFMA16(ka1, qf1, s0);
      bf16x8 ke = {};
      if (g == 0)
        ke = *(const bf16x8*)&keg_b[(size_t)(jbase + j4 * 16 + li) * 8];
      dac[j4] = MFMA16(ke, qe, z);
    }

    // p = exp2(s*scale*log2e - M2) * w(d^2); no max tracking (fixed bound)
    #pragma unroll
    for (int j4 = 0; j4 < 4; j4++) {
      float p[4];
      #pragma unroll
      for (int r = 0; r < 4; r++) {
        float u = fmaxf(dac[j4][r], 0.0f);
        float fi = u * 32.0f;
        int idx = (int)fi;
        idx = idx < 2047 ? idx : 2047;
        float fr = fi - (float)idx;
        union { u32 uu; __half2 h2; } cv;
        cv.uu = tblS[idx];
        float wv = __low2float(cv.h2) + fr * __high2float(cv.h2);
        float e = exp2f(fmaf(sac[j4][r], SC2, -M2CONST));
        p[r] = e * wv;
        lacc += p[r];
      }
      uint2 pv;
      pv.x = f2us(p[0]) | ((u32)f2us(p[1]) << 16);
      pv.y = f2us(p[2]) | ((u32)f2us(p[3]) << 16);
      *(uint2*)&Pl[(w * 16 + li) * 72 + j4 * 16 + g * 4] = pv;
    }

    // PV (wave-local Pl roundtrip; no barrier needed within wave)
    bf16x8 pf0 = *(const bf16x8*)&Pl[(w * 16 + li) * 72 + g * 8];
    bf16x8 pf1 = *(const bf16x8*)&Pl[(w * 16 + li) * 72 + 32 + g * 8];
    #pragma unroll
    for (int dt = 0; dt < 4; dt++) {
      bf16x8 v0 = *(const bf16x8*)&Vtl[(dt * 16 + li) * 72 + g * 8];
      bf16x8 v1 = *(const bf16x8*)&Vtl[(dt * 16 + li) * 72 + 32 + g * 8];
      oacc[dt] = MFMA16(pf0, v0, oacc[dt]);
      oacc[dt] = MFMA16(pf1, v1, oacc[dt]);
    }
  }

  float lf = lacc;
  lf += __shfl_xor(lf, 16);
  lf += __shfl_xor(lf, 32);

  const size_t obase =
      ((size_t)(sidx * 16 + b * 8 + h) * 1024 + qt * 64 + w * 16) * 64;
  #pragma unroll
  for (int dt = 0; dt < 4; dt++)
    #pragma unroll
    for (int r = 0; r < 4; r++)
      Op[obase + (size_t)(4 * g + r) * 64 + dt * 16 + li] = oacc[dt][r];
  if (g == 0)
    Lp[(size_t)(sidx * 16 + b * 8 + h) * 1024 + qt * 64 + w * 16 + li] = lf;
}

// ---------------- combine split partials, normalize, write bf16 AO ---------
__global__ __launch_bounds__(256) void combine_kernel(const float* __restrict__ Op,
                                                      const float* __restrict__ Lp,
                                                      u16* __restrict__ AOb) {
  int tid = blockIdx.x * 256 + threadIdx.x;   // 262144 total
  int d4 = tid & 15, rh = tid >> 4;
  int bh = rh >> 10, qrow = rh & 1023;
  f32x4 o = {};
  float lsum = 0.0f;
  #pragma unroll
  for (int s = 0; s < 4; s++) {
    f32x4 v = *(const f32x4*)&Op[((size_t)(s * 16 + bh) * 1024 + qrow) * 64 + d4 * 4];
    o += v;
    lsum += Lp[(size_t)(s * 16 + bh) * 1024 + qrow];
  }
  float inv = 1.0f / lsum;
  uint2 pk;
  pk.x = f2us(o[0] * inv) | ((u32)f2us(o[1] * inv) << 16);
  pk.y = f2us(o[2] * inv) | ((u32)f2us(o[3] * inv) << 16);
  *(uint2*)&AOb[((size_t)(bh >> 3) * NQ + qrow) * 512 + (bh & 7) * 64 + d4 * 4] = pk;
}

extern "C" void kernel_launch(void* const* d_in, const int* in_sizes, int n_in,
                              void* d_out, int out_size, void* d_ws, size_t ws_size,
                              hipStream_t stream) {
  const float* q_in      = (const float*)d_in[0];
  const float* kv_in     = (const float*)d_in[1];
  const float* q_coords  = (const float*)d_in[2];
  const float* kv_coords = (const float*)d_in[3];
  const float* Wq        = (const float*)d_in[4];
  const float* Wk        = (const float*)d_in[5];
  const float* Wv        = (const float*)d_in[6];
  const float* Wo        = (const float*)d_in[7];
  const float* W1        = (const float*)d_in[8];
  const float* b1        = (const float*)d_in[9];
  const float* W2        = (const float*)d_in[10];
  const float* b2        = (const float*)d_in[11];

  char* p = (char*)d_ws;
  u16* qb   = (u16*)p; p += (size_t)2048 * 512 * 2;
  u16* kvb  = (u16*)p; p += (size_t)4096 * 512 * 2;
  u16* Wqt  = (u16*)p; p += (size_t)512 * 512 * 2;
  u16* Wkt  = (u16*)p; p += (size_t)512 * 512 * 2;
  u16* Wvt  = (u16*)p; p += (size_t)512 * 512 * 2;
  u16* Wot  = (u16*)p; p += (size_t)512 * 512 * 2;
  u16* Qp   = (u16*)p; p += (size_t)2048 * 512 * 2;
  u16* Kp   = (u16*)p; p += (size_t)4096 * 512 * 2;
  u16* Vtp  = (u16*)p; p += (size_t)4096 * 512 * 2;
  u16* AOb  = (u16*)p; p += (size_t)2048 * 512 * 2;
  u32* tblp = (u32*)p; p += (size_t)8 * 2048 * 4;
  u16* keg  = (u16*)p; p += (size_t)4096 * 8 * 2;
  float* Opart = (float*)p; p += (size_t)4 * 16 * 1024 * 64 * 4;
  float* Lpart = (float*)p; p += (size_t)4 * 16 * 1024 * 4;

  castall_kernel<<<3072, 256, 0, stream>>>(q_in, kv_in, qb, kvb);
  tcast4_kernel<<<dim3(8, 8, 4), 256, 0, stream>>>(Wq, Wk, Wv, Wo, Wqt, Wkt, Wvt, Wot);
  tablekeg_kernel<<<24, 256, 0, stream>>>(W1, b1, W2, b2, tblp, kv_coords, keg);
  gemm_mfma<32, 0><<<dim3(64, 8), 256, 0, stream>>>(qb, Wqt, Qp);
  gemm_kv<<<dim3(64, 8), 256, 0, stream>>>(kvb, Wkt, Wvt, Kp, Vtp);
  attn_kernel<<<dim3(64, 8, 2), 256, 0, stream>>>(Qp, Kp, Vtp, q_coords, keg,
                                                  tblp, Opart, Lpart);
  combine_kernel<<<1024, 256, 0, stream>>>(Opart, Lpart, AOb);
  gemm_mfma<32, 1><<<dim3(64, 8), 256, 0, stream>>>(AOb, Wot, d_out);
}

// Round 5
// 158.212 us; speedup vs baseline: 3.1239x; 1.0450x over previous
//
#include <hip/hip_runtime.h>
#include <hip/hip_bf16.h>
#include <hip/hip_fp16.h>
#include <math.h>

typedef short bf16x8 __attribute__((ext_vector_type(8)));
typedef float f32x4 __attribute__((ext_vector_type(4)));
typedef unsigned short u16;
typedef unsigned int u32;

#define NH 8
#define BB 2
#define NQ 1024
#define NK 2048
#define M2CONST 6.4921250  // 4.5 * log2(e), folded into poly c0
#define SC2 0.18033688f    // 0.125 * log2(e)

#define MFMA16(a, b, c) __builtin_amdgcn_mfma_f32_16x16x32_bf16(a, b, c, 0, 0, 0)

// Chebyshev nodes over [0,16], x_i = 8 + 8*cos(pi*(2i+1)/12)
__device__ __constant__ double XN_D[6] = {15.727406610312546, 13.656854249492380,
                                          10.070552360820166, 5.9294476391798335,
                                          2.3431457505076194, 0.27259338968745405};
#define XN0 15.727406610312546f
#define XN1 13.656854249492380f
#define XN2 10.070552360820166f
#define XN3 5.9294476391798335f
#define XN4 2.3431457505076194f

static __device__ __forceinline__ u16 f2us(float x) {
  union { __hip_bfloat16 b; u16 u; } cv;
  cv.b = __float2bfloat16(x);
  return cv.u;
}

static __device__ __forceinline__ bf16x8 pack8(float4 a, float4 b) {
  bf16x8 r;
  r[0] = (short)f2us(a.x); r[1] = (short)f2us(a.y);
  r[2] = (short)f2us(a.z); r[3] = (short)f2us(a.w);
  r[4] = (short)f2us(b.x); r[5] = (short)f2us(b.y);
  r[6] = (short)f2us(b.z); r[7] = (short)f2us(b.w);
  return r;
}

// ============ setup: weight transpose-casts + poly fit + keg ===============
// grid 273: [0,256) tcast (4 matrices x 8x8 tiles); 256 = poly fit; [257,273) keg
__global__ __launch_bounds__(256) void setup_kernel(
    const float* __restrict__ Wq, const float* __restrict__ Wk,
    const float* __restrict__ Wv, const float* __restrict__ Wo,
    u16* __restrict__ Tq, u16* __restrict__ Tk,
    u16* __restrict__ Tv, u16* __restrict__ To,
    const float* __restrict__ W1, const float* __restrict__ b1,
    const float* __restrict__ W2, const float* __restrict__ b2,
    float* __restrict__ polyc,
    const float* __restrict__ kc, u16* __restrict__ keg) {
  const int blk = blockIdx.x, t = threadIdx.x;
  if (blk < 256) {
    __shared__ u16 tile[64][65];
    const float* W; u16* Wt;
    switch (blk >> 6) {
      case 0: W = Wq; Wt = Tq; break;
      case 1: W = Wk; Wt = Tk; break;
      case 2: W = Wv; Wt = Tv; break;
      default: W = Wo; Wt = To; break;
    }
    const int rem = blk & 63;
    const int k0 = (rem >> 3) * 64, n0 = (rem & 7) * 64;
    const int r = t >> 4, c4 = (t & 15) * 4;
    #pragma unroll
    for (int p = 0; p < 4; p++) {
      int row = p * 16 + r;
      float4 v = *(const float4*)&W[(size_t)(k0 + row) * 512 + n0 + c4];
      tile[row][c4 + 0] = f2us(v.x);
      tile[row][c4 + 1] = f2us(v.y);
      tile[row][c4 + 2] = f2us(v.z);
      tile[row][c4 + 3] = f2us(v.w);
    }
    __syncthreads();
    #pragma unroll
    for (int p = 0; p < 4; p++) {
      int n = p * 16 + r;
      u16 u0 = tile[c4 + 0][n], u1 = tile[c4 + 1][n];
      u16 u2 = tile[c4 + 2][n], u3 = tile[c4 + 3][n];
      uint2 o;
      o.x = u0 | ((u32)u1 << 16);
      o.y = u2 | ((u32)u3 << 16);
      *(uint2*)&Wt[(size_t)(n0 + n) * 512 + k0 + c4] = o;
    }
  } else if (blk == 256) {
    // fit g_h(d) = log2e*f_h(d) - M2 with Newton form at 6 Chebyshev nodes
    __shared__ double fv[6][8];
    if (t < 48) {
      int i = t >> 3, h = t & 7;
      double x = XN_D[i];
      double acc = (double)b2[h];
      for (int r = 0; r < 64; r++) {
        double u = x * (double)W1[r] + (double)b1[r];
        double s = u / (1.0 + exp(-u));
        acc += s * (double)W2[r * 8 + h];
      }
      fv[i][h] = acc * 1.4426950408889634 - M2CONST;
    }
    __syncthreads();
    if (t < 8) {
      int h = t;
      double c[6];
      #pragma unroll
      for (int i = 0; i < 6; i++) c[i] = fv[i][h];
      for (int k = 1; k < 6; k++)
        for (int i = 5; i >= k; i--)
          c[i] = (c[i] - c[i - 1]) / (XN_D[i] - XN_D[i - k]);
      #pragma unroll
      for (int j = 0; j < 6; j++) polyc[h * 8 + j] = (float)c[j];
    }
  } else {
    int r = (blk - 257) * 256 + t;   // 0..4095 kv rows
    float kx = kc[(size_t)r * 3], ky = kc[(size_t)r * 3 + 1], kz = kc[(size_t)r * 3 + 2];
    uint4 o;
    o.x = f2us(-2.0f * kx) | ((u32)f2us(-2.0f * ky) << 16);
    o.y = f2us(-2.0f * kz) | ((u32)f2us(1.0f) << 16);
    o.z = (u32)f2us(kx * kx + ky * ky + kz * kz);
    o.w = 0;
    *(uint4*)&keg[(size_t)r * 8] = o;
  }
}

// ===== fused Q/K/V projection from fp32 inputs (cast in staging), BK=64 ====
// grid (96, 8): x<32 -> Q rows (Wq); x>=32 -> KV rows (Wk + Wv fused)
__global__ __launch_bounds__(256) void gemm_qkv(
    const float* __restrict__ q_in, const float* __restrict__ kv_in,
    const u16* __restrict__ Wqt, const u16* __restrict__ Wkt,
    const u16* __restrict__ Wvt, u16* __restrict__ Qp,
    u16* __restrict__ Kp, u16* __restrict__ Vtp) {
  __shared__ u16 As[64 * 72];
  __shared__ u16 Bs[64 * 72];
  __shared__ u16 Bs2[64 * 72];
  const int t = threadIdx.x;
  const int w = t >> 6, l = t & 63, g = l >> 4, li = l & 15;
  const int bx = blockIdx.x;
  const bool isQ = bx < 32;
  const int m0 = (isQ ? bx : bx - 32) * 64, n0 = blockIdx.y * 64;
  const float* A = isQ ? q_in : kv_in;
  const u16* B1 = isQ ? Wqt : Wkt;
  const int ms = (w & 1) * 32, ns = (w >> 1) * 32;
  const int ar = t >> 2, ac = (t & 3) * 16;   // A staging: row, col16
  f32x4 acc[2][2] = {}, accV[2][2] = {};

  for (int kt = 0; kt < 512; kt += 64) {
    float4 a4[4];
    #pragma unroll
    for (int q = 0; q < 4; q++)
      a4[q] = *(const float4*)&A[(size_t)(m0 + ar) * 512 + kt + ac + 4 * q];
    bf16x8 bk[2], bv2[2];
    #pragma unroll
    for (int p = 0; p < 2; p++) {
      int f = p * 256 + t, r = f >> 3, c8 = (f & 7) * 8;
      bk[p] = *(const bf16x8*)&B1[(size_t)(n0 + r) * 512 + kt + c8];
    }
    if (!isQ) {
      #pragma unroll
      for (int p = 0; p < 2; p++) {
        int f = p * 256 + t, r = f >> 3, c8 = (f & 7) * 8;
        bv2[p] = *(const bf16x8*)&Wvt[(size_t)(n0 + r) * 512 + kt + c8];
      }
    }
    __syncthreads();
    *(bf16x8*)&As[ar * 72 + ac] = pack8(a4[0], a4[1]);
    *(bf16x8*)&As[ar * 72 + ac + 8] = pack8(a4[2], a4[3]);
    #pragma unroll
    for (int p = 0; p < 2; p++) {
      int f = p * 256 + t, r = f >> 3, c8 = (f & 7) * 8;
      *(bf16x8*)&Bs[r * 72 + c8] = bk[p];
    }
    if (!isQ) {
      #pragma unroll
      for (int p = 0; p < 2; p++) {
        int f = p * 256 + t, r = f >> 3, c8 = (f & 7) * 8;
        *(bf16x8*)&Bs2[r * 72 + c8] = bv2[p];
      }
    }
    __syncthreads();
    #pragma unroll
    for (int ks = 0; ks < 2; ks++) {
      bf16x8 a0 = *(const bf16x8*)&As[(ms + li) * 72 + ks * 32 + g * 8];
      bf16x8 a1 = *(const bf16x8*)&As[(ms + 16 + li) * 72 + ks * 32 + g * 8];
      bf16x8 k0 = *(const bf16x8*)&Bs[(ns + li) * 72 + ks * 32 + g * 8];
      bf16x8 k1 = *(const bf16x8*)&Bs[(ns + 16 + li) * 72 + ks * 32 + g * 8];
      acc[0][0] = MFMA16(a0, k0, acc[0][0]);
      acc[0][1] = MFMA16(a0, k1, acc[0][1]);
      acc[1][0] = MFMA16(a1, k0, acc[1][0]);
      acc[1][1] = MFMA16(a1, k1, acc[1][1]);
      if (!isQ) {
        bf16x8 v0 = *(const bf16x8*)&Bs2[(ns + li) * 72 + ks * 32 + g * 8];
        bf16x8 v1 = *(const bf16x8*)&Bs2[(ns + 16 + li) * 72 + ks * 32 + g * 8];
        accV[0][0] = MFMA16(a0, v0, accV[0][0]);
        accV[0][1] = MFMA16(a0, v1, accV[0][1]);
        accV[1][0] = MFMA16(a1, v0, accV[1][0]);
        accV[1][1] = MFMA16(a1, v1, accV[1][1]);
      }
    }
  }
  #pragma unroll
  for (int mi = 0; mi < 2; mi++) {
    #pragma unroll
    for (int ni = 0; ni < 2; ni++) {
      int row = m0 + ms + mi * 16 + 4 * g;
      int col = n0 + ns + ni * 16 + li;
      f32x4 vk = acc[mi][ni];
      if (isQ) {
        #pragma unroll
        for (int r = 0; r < 4; r++) Qp[(size_t)(row + r) * 512 + col] = f2us(vk[r]);
      } else {
        #pragma unroll
        for (int r = 0; r < 4; r++) Kp[(size_t)(row + r) * 512 + col] = f2us(vk[r]);
        f32x4 vv = accV[mi][ni];
        int bb = row >> 11, j = row & 2047;
        int hh = col >> 6, d = col & 63;
        uint2 o;
        o.x = f2us(vv[0]) | ((u32)f2us(vv[1]) << 16);
        o.y = f2us(vv[2]) | ((u32)f2us(vv[3]) << 16);
        *(uint2*)&Vtp[((size_t)((bb * 8 + hh) * 64 + d)) * 2048 + j] = o;
      }
    }
  }
}

// ---------------- bf16 MFMA GEMM (Wo pass), TM=32, fp32 out ----------------
__global__ __launch_bounds__(256) void gemm_wo(const u16* __restrict__ A,
                                               const u16* __restrict__ Bt,
                                               float* __restrict__ C) {
  __shared__ u16 As[32 * 72];
  __shared__ u16 Bs[64 * 72];
  const int t = threadIdx.x;
  const int w = t >> 6, l = t & 63, g = l >> 4, li = l & 15;
  const int m0 = blockIdx.x * 32, n0 = blockIdx.y * 64;
  const int ms = (w & 1) * 16, ns = (w >> 1) * 32;
  f32x4 acc[2] = {};
  for (int kt = 0; kt < 512; kt += 64) {
    bf16x8 av, bv[2];
    {
      int r = t >> 3, c8 = (t & 7) * 8;
      av = *(const bf16x8*)&A[(size_t)(m0 + r) * 512 + kt + c8];
    }
    #pragma unroll
    for (int p = 0; p < 2; p++) {
      int f = p * 256 + t, r = f >> 3, c8 = (f & 7) * 8;
      bv[p] = *(const bf16x8*)&Bt[(size_t)(n0 + r) * 512 + kt + c8];
    }
    __syncthreads();
    {
      int r = t >> 3, c8 = (t & 7) * 8;
      *(bf16x8*)&As[r * 72 + c8] = av;
    }
    #pragma unroll
    for (int p = 0; p < 2; p++) {
      int f = p * 256 + t, r = f >> 3, c8 = (f & 7) * 8;
      *(bf16x8*)&Bs[r * 72 + c8] = bv[p];
    }
    __syncthreads();
    #pragma unroll
    for (int ks = 0; ks < 2; ks++) {
      bf16x8 af = *(const bf16x8*)&As[(ms + li) * 72 + ks * 32 + g * 8];
      bf16x8 b0 = *(const bf16x8*)&Bs[(ns + li) * 72 + ks * 32 + g * 8];
      bf16x8 b1 = *(const bf16x8*)&Bs[(ns + 16 + li) * 72 + ks * 32 + g * 8];
      acc[0] = MFMA16(af, b0, acc[0]);
      acc[1] = MFMA16(af, b1, acc[1]);
    }
  }
  #pragma unroll
  for (int ni = 0; ni < 2; ni++) {
    f32x4 v = acc[ni];
    int row = m0 + ms + 4 * g;
    int col = n0 + ns + ni * 16 + li;
    #pragma unroll
    for (int r = 0; r < 4; r++) C[(size_t)(row + r) * 512 + col] = v[r];
  }
}

// -------- fixed-max flash attention, split-K x4, per-head poly bias --------
// grid (64, 8, 2): x = qt*4 + split; 4 waves/block, wave = 16 q-rows
__global__ __launch_bounds__(256, 4) void attn_kernel(
    const u16* __restrict__ Qb, const u16* __restrict__ Kb,
    const u16* __restrict__ Vt, const float* __restrict__ qc,
    const u16* __restrict__ keg, const float* __restrict__ polyc,
    float* __restrict__ Op, float* __restrict__ Lp) {
  __shared__ u16 Kl[64 * 72];
  __shared__ u16 Vtl[64 * 72];
  __shared__ u16 Pl[64 * 72];

  const int t = threadIdx.x;
  const int w = t >> 6, l = t & 63, g = l >> 4, li = l & 15;
  const int qt = blockIdx.x >> 2, sidx = blockIdx.x & 3;
  const int h = blockIdx.y, b = blockIdx.z;

  // per-head Newton coefficients (uniform -> scalar regs)
  const float c0 = polyc[h * 8 + 0], c1 = polyc[h * 8 + 1];
  const float c2 = polyc[h * 8 + 2], c3 = polyc[h * 8 + 3];
  const float c4 = polyc[h * 8 + 4], c5 = polyc[h * 8 + 5];

  const int qrow = qt * 64 + w * 16 + li;
  const size_t qg = (size_t)b * NQ + qrow;
  bf16x8 qf0 = *(const bf16x8*)&Qb[qg * 512 + h * 64 + g * 8];
  bf16x8 qf1 = *(const bf16x8*)&Qb[qg * 512 + h * 64 + 32 + g * 8];
  float qx = qc[qg * 3], qy = qc[qg * 3 + 1], qz = qc[qg * 3 + 2];
  bf16x8 qe = {};
  if (g == 0) {
    qe[0] = (short)f2us(qx);
    qe[1] = (short)f2us(qy);
    qe[2] = (short)f2us(qz);
    qe[3] = (short)f2us(qx * qx + qy * qy + qz * qz);
    qe[4] = (short)f2us(1.0f);
  }

  f32x4 oacc[4] = {};
  float lacc = 0.0f;

  const u16* Kg = Kb + (size_t)b * NK * 512 + h * 64;
  const u16* Vg = Vt + (size_t)((b * 8 + h) * 64) * 2048;
  const u16* keg_b = keg + (size_t)b * NK * 8;

  for (int it = 0; it < 8; it++) {
    const int jbase = sidx * 512 + it * 64;
    __syncthreads();
    #pragma unroll
    for (int pp = 0; pp < 2; pp++) {
      int f = pp * 256 + t, row = f >> 3, c8 = (f & 7) * 8;
      *(bf16x8*)&Kl[row * 72 + c8] =
          *(const bf16x8*)&Kg[(size_t)(jbase + row) * 512 + c8];
      *(bf16x8*)&Vtl[row * 72 + c8] =
          *(const bf16x8*)&Vg[(size_t)row * 2048 + jbase + c8];
    }
    __syncthreads();

    // S^T = K Q^T and d^2 via augmented MFMA (col=i=li, row=j=4g+r)
    f32x4 sac[4], dac[4];
    #pragma unroll
    for (int j4 = 0; j4 < 4; j4++) {
      bf16x8 ka0 = *(const bf16x8*)&Kl[(j4 * 16 + li) * 72 + g * 8];
      bf16x8 ka1 = *(const bf16x8*)&Kl[(j4 * 16 + li) * 72 + 32 + g * 8];
      f32x4 z = {};
      f32x4 s0 = MFMA16(ka0, qf0, z);
      sac[j4] = MFMA16(ka1, qf1, s0);
      bf16x8 ke = {};
      if (g == 0)
        ke = *(const bf16x8*)&keg_b[(size_t)(jbase + j4 * 16 + li) * 8];
      dac[j4] = MFMA16(ke, qe, z);
    }

    // p = exp2(s*SC2 + g(d)), g = Newton poly (includes -M2)
    #pragma unroll
    for (int j4 = 0; j4 < 4; j4++) {
      float p[4];
      #pragma unroll
      for (int r = 0; r < 4; r++) {
        float u = fmaxf(dac[j4][r], 0.0f);
        float d = fminf(sqrtf(u), 16.0f);
        float gp = c5;
        gp = fmaf(gp, d - XN4, c4);
        gp = fmaf(gp, d - XN3, c3);
        gp = fmaf(gp, d - XN2, c2);
        gp = fmaf(gp, d - XN1, c1);
        gp = fmaf(gp, d - XN0, c0);
        p[r] = exp2f(fmaf(sac[j4][r], SC2, gp));
        lacc += p[r];
      }
      uint2 pv;
      pv.x = f2us(p[0]) | ((u32)f2us(p[1]) << 16);
      pv.y = f2us(p[2]) | ((u32)f2us(p[3]) << 16);
      *(uint2*)&Pl[(w * 16 + li) * 72 + j4 * 16 + g * 4] = pv;
    }

    // PV (wave-local Pl roundtrip)
    bf16x8 pf0 = *(const bf16x8*)&Pl[(w * 16 + li) * 72 + g * 8];
    bf16x8 pf1 = *(const bf16x8*)&Pl[(w * 16 + li) * 72 + 32 + g * 8];
    #pragma unroll
    for (int dt = 0; dt < 4; dt++) {
      bf16x8 v0 = *(const bf16x8*)&Vtl[(dt * 16 + li) * 72 + g * 8];
      bf16x8 v1 = *(const bf16x8*)&Vtl[(dt * 16 + li) * 72 + 32 + g * 8];
      oacc[dt] = MFMA16(pf0, v0, oacc[dt]);
      oacc[dt] = MFMA16(pf1, v1, oacc[dt]);
    }
  }

  float lf = lacc;
  lf += __shfl_xor(lf, 16);
  lf += __shfl_xor(lf, 32);

  const size_t obase =
      ((size_t)(sidx * 16 + b * 8 + h) * 1024 + qt * 64 + w * 16) * 64;
  #pragma unroll
  for (int dt = 0; dt < 4; dt++)
    #pragma unroll
    for (int r = 0; r < 4; r++)
      Op[obase + (size_t)(4 * g + r) * 64 + dt * 16 + li] = oacc[dt][r];
  if (g == 0)
    Lp[(size_t)(sidx * 16 + b * 8 + h) * 1024 + qt * 64 + w * 16 + li] = lf;
}

// ---------------- combine split partials, normalize, write bf16 AO ---------
__global__ __launch_bounds__(256) void combine_kernel(const float* __restrict__ Op,
                                                      const float* __restrict__ Lp,
                                                      u16* __restrict__ AOb) {
  int tid = blockIdx.x * 256 + threadIdx.x;   // 262144 total
  int d4 = tid & 15, rh = tid >> 4;
  int bh = rh >> 10, qrow = rh & 1023;
  f32x4 o = {};
  float lsum = 0.0f;
  #pragma unroll
  for (int s = 0; s < 4; s++) {
    f32x4 v = *(const f32x4*)&Op[((size_t)(s * 16 + bh) * 1024 + qrow) * 64 + d4 * 4];
    o += v;
    lsum += Lp[(size_t)(s * 16 + bh) * 1024 + qrow];
  }
  float inv = 1.0f / lsum;
  uint2 pk;
  pk.x = f2us(o[0] * inv) | ((u32)f2us(o[1] * inv) << 16);
  pk.y = f2us(o[2] * inv) | ((u32)f2us(o[3] * inv) << 16);
  *(uint2*)&AOb[((size_t)(bh >> 3) * NQ + qrow) * 512 + (bh & 7) * 64 + d4 * 4] = pk;
}

extern "C" void kernel_launch(void* const* d_in, const int* in_sizes, int n_in,
                              void* d_out, int out_size, void* d_ws, size_t ws_size,
                              hipStream_t stream) {
  const float* q_in      = (const float*)d_in[0];
  const float* kv_in     = (const float*)d_in[1];
  const float* q_coords  = (const float*)d_in[2];
  const float* kv_coords = (const float*)d_in[3];
  const float* Wq        = (const float*)d_in[4];
  const float* Wk        = (const float*)d_in[5];
  const float* Wv        = (const float*)d_in[6];
  const float* Wo        = (const float*)d_in[7];
  const float* W1        = (const float*)d_in[8];
  const float* b1        = (const float*)d_in[9];
  const float* W2        = (const float*)d_in[10];
  const float* b2        = (const float*)d_in[11];

  char* p = (char*)d_ws;
  u16* Wqt  = (u16*)p; p += (size_t)512 * 512 * 2;
  u16* Wkt  = (u16*)p; p += (size_t)512 * 512 * 2;
  u16* Wvt  = (u16*)p; p += (size_t)512 * 512 * 2;
  u16* Wot  = (u16*)p; p += (size_t)512 * 512 * 2;
  u16* Qp   = (u16*)p; p += (size_t)2048 * 512 * 2;
  u16* Kp   = (u16*)p; p += (size_t)4096 * 512 * 2;
  u16* Vtp  = (u16*)p; p += (size_t)4096 * 512 * 2;
  u16* AOb  = (u16*)p; p += (size_t)2048 * 512 * 2;
  u16* keg  = (u16*)p; p += (size_t)4096 * 8 * 2;
  float* polyc = (float*)p; p += (size_t)64 * 4;
  p = (char*)(((size_t)p + 255) & ~(size_t)255);
  float* Opart = (float*)p; p += (size_t)4 * 16 * 1024 * 64 * 4;
  float* Lpart = (float*)p; p += (size_t)4 * 16 * 1024 * 4;

  setup_kernel<<<273, 256, 0, stream>>>(Wq, Wk, Wv, Wo, Wqt, Wkt, Wvt, Wot,
                                        W1, b1, W2, b2, polyc, kv_coords, keg);
  gemm_qkv<<<dim3(96, 8), 256, 0, stream>>>(q_in, kv_in, Wqt, Wkt, Wvt,
                                            Qp, Kp, Vtp);
  attn_kernel<<<dim3(64, 8, 2), 256, 0, stream>>>(Qp, Kp, Vtp, q_coords, keg,
                                                  polyc, Opart, Lpart);
  combine_kernel<<<1024, 256, 0, stream>>>(Opart, Lpart, AOb);
  gemm_wo<<<dim3(64, 8), 256, 0, stream>>>(AOb, Wot, (float*)d_out);
}

// Round 6
// 152.711 us; speedup vs baseline: 3.2364x; 1.0360x over previous
//
#include <hip/hip_runtime.h>
#include <hip/hip_bf16.h>
#include <math.h>

typedef short bf16x8 __attribute__((ext_vector_type(8)));
typedef float f32x4 __attribute__((ext_vector_type(4)));
typedef unsigned short u16;
typedef unsigned int u32;

#define NH 8
#define BB 2
#define NQ 1024
#define NK 2048
#define M2CONST 6.4921250  // 4.5 * log2(e), folded into poly c0
#define SC2 0.18033688f    // 0.125 * log2(e)

#define MFMA16(a, b, c) __builtin_amdgcn_mfma_f32_16x16x32_bf16(a, b, c, 0, 0, 0)

// Chebyshev nodes over [0,16], x_i = 8 + 8*cos(pi*(2i+1)/12)
__device__ __constant__ double XN_D[6] = {15.727406610312546, 13.656854249492380,
                                          10.070552360820166, 5.9294476391798335,
                                          2.3431457505076194, 0.27259338968745405};
#define XN0 15.727406610312546f
#define XN1 13.656854249492380f
#define XN2 10.070552360820166f
#define XN3 5.9294476391798335f
#define XN4 2.3431457505076194f

// slow (cold-path) bf16 cast
static __device__ __forceinline__ u16 f2us(float x) {
  union { __hip_bfloat16 b; u16 u; } cv;
  cv.b = __float2bfloat16(x);
  return cv.u;
}

// fast RNE bf16 round: result in bits [31:16] (valid for finite values)
static __device__ __forceinline__ u32 bfr(float x) {
  u32 u = __builtin_bit_cast(u32, x);
  return u + 0x7FFFu + ((u >> 16) & 1u);
}
static __device__ __forceinline__ u32 pk2(float lo, float hi) {
  return (bfr(lo) >> 16) | (bfr(hi) & 0xFFFF0000u);
}
static __device__ __forceinline__ u16 bfs(float x) { return (u16)(bfr(x) >> 16); }

static __device__ __forceinline__ bf16x8 pack8(float4 a, float4 b) {
  union { bf16x8 v; uint4 u; } cv;
  cv.u.x = pk2(a.x, a.y);
  cv.u.y = pk2(a.z, a.w);
  cv.u.z = pk2(b.x, b.y);
  cv.u.w = pk2(b.z, b.w);
  return cv.v;
}

// ============ setup: weight transpose-casts + poly fit + keg ===============
// grid 273: [0,256) tcast (4 matrices x 8x8 tiles); 256 = poly fit; [257,273) keg
__global__ __launch_bounds__(256) void setup_kernel(
    const float* __restrict__ Wq, const float* __restrict__ Wk,
    const float* __restrict__ Wv, const float* __restrict__ Wo,
    u16* __restrict__ Tq, u16* __restrict__ Tk,
    u16* __restrict__ Tv, u16* __restrict__ To,
    const float* __restrict__ W1, const float* __restrict__ b1,
    const float* __restrict__ W2, const float* __restrict__ b2,
    float* __restrict__ polyc,
    const float* __restrict__ kc, u16* __restrict__ keg) {
  const int blk = blockIdx.x, t = threadIdx.x;
  if (blk < 256) {
    __shared__ u16 tile[64][65];
    const float* W; u16* Wt;
    switch (blk >> 6) {
      case 0: W = Wq; Wt = Tq; break;
      case 1: W = Wk; Wt = Tk; break;
      case 2: W = Wv; Wt = Tv; break;
      default: W = Wo; Wt = To; break;
    }
    const int rem = blk & 63;
    const int k0 = (rem >> 3) * 64, n0 = (rem & 7) * 64;
    const int r = t >> 4, c4 = (t & 15) * 4;
    #pragma unroll
    for (int p = 0; p < 4; p++) {
      int row = p * 16 + r;
      float4 v = *(const float4*)&W[(size_t)(k0 + row) * 512 + n0 + c4];
      tile[row][c4 + 0] = f2us(v.x);
      tile[row][c4 + 1] = f2us(v.y);
      tile[row][c4 + 2] = f2us(v.z);
      tile[row][c4 + 3] = f2us(v.w);
    }
    __syncthreads();
    #pragma unroll
    for (int p = 0; p < 4; p++) {
      int n = p * 16 + r;
      u16 u0 = tile[c4 + 0][n], u1 = tile[c4 + 1][n];
      u16 u2 = tile[c4 + 2][n], u3 = tile[c4 + 3][n];
      uint2 o;
      o.x = u0 | ((u32)u1 << 16);
      o.y = u2 | ((u32)u3 << 16);
      *(uint2*)&Wt[(size_t)(n0 + n) * 512 + k0 + c4] = o;
    }
  } else if (blk == 256) {
    // fit g_h(d) = log2e*f_h(d) - M2 with Newton form at 6 Chebyshev nodes
    __shared__ double fv[6][8];
    if (t < 48) {
      int i = t >> 3, h = t & 7;
      double x = XN_D[i];
      double acc = (double)b2[h];
      for (int r = 0; r < 64; r++) {
        double u = x * (double)W1[r] + (double)b1[r];
        double s = u / (1.0 + exp(-u));
        acc += s * (double)W2[r * 8 + h];
      }
      fv[i][h] = acc * 1.4426950408889634 - M2CONST;
    }
    __syncthreads();
    if (t < 8) {
      int h = t;
      double c[6];
      #pragma unroll
      for (int i = 0; i < 6; i++) c[i] = fv[i][h];
      for (int k = 1; k < 6; k++)
        for (int i = 5; i >= k; i--)
          c[i] = (c[i] - c[i - 1]) / (XN_D[i] - XN_D[i - k]);
      #pragma unroll
      for (int j = 0; j < 6; j++) polyc[h * 8 + j] = (float)c[j];
    }
  } else {
    int r = (blk - 257) * 256 + t;   // 0..4095 kv rows
    float kx = kc[(size_t)r * 3], ky = kc[(size_t)r * 3 + 1], kz = kc[(size_t)r * 3 + 2];
    uint4 o;
    o.x = f2us(-2.0f * kx) | ((u32)f2us(-2.0f * ky) << 16);
    o.y = f2us(-2.0f * kz) | ((u32)f2us(1.0f) << 16);
    o.z = (u32)f2us(kx * kx + ky * ky + kz * kz);
    o.w = 0;
    *(uint4*)&keg[(size_t)r * 8] = o;
  }
}

// ===== fused Q/K/V projection from fp32 inputs (cast in staging), BK=64 ====
// grid (96, 8): x<32 -> Q rows (Wq); x>=32 -> KV rows (Wk + Wv fused)
__global__ __launch_bounds__(256) void gemm_qkv(
    const float* __restrict__ q_in, const float* __restrict__ kv_in,
    const u16* __restrict__ Wqt, const u16* __restrict__ Wkt,
    const u16* __restrict__ Wvt, u16* __restrict__ Qp,
    u16* __restrict__ Kp, u16* __restrict__ Vtp) {
  __shared__ u16 As[64 * 72];
  __shared__ u16 Bs[64 * 72];
  __shared__ u16 Bs2[64 * 72];
  const int t = threadIdx.x;
  const int w = t >> 6, l = t & 63, g = l >> 4, li = l & 15;
  const int bx = blockIdx.x;
  const bool isQ = bx < 32;
  const int m0 = (isQ ? bx : bx - 32) * 64, n0 = blockIdx.y * 64;
  const float* A = isQ ? q_in : kv_in;
  const u16* B1 = isQ ? Wqt : Wkt;
  const int ms = (w & 1) * 32, ns = (w >> 1) * 32;
  const int ar = t >> 2, ac = (t & 3) * 16;   // A staging: row, col16
  f32x4 acc[2][2] = {}, accV[2][2] = {};

  for (int kt = 0; kt < 512; kt += 64) {
    float4 a4[4];
    #pragma unroll
    for (int q = 0; q < 4; q++)
      a4[q] = *(const float4*)&A[(size_t)(m0 + ar) * 512 + kt + ac + 4 * q];
    bf16x8 bk[2], bv2[2];
    #pragma unroll
    for (int p = 0; p < 2; p++) {
      int f = p * 256 + t, r = f >> 3, c8 = (f & 7) * 8;
      bk[p] = *(const bf16x8*)&B1[(size_t)(n0 + r) * 512 + kt + c8];
    }
    if (!isQ) {
      #pragma unroll
      for (int p = 0; p < 2; p++) {
        int f = p * 256 + t, r = f >> 3, c8 = (f & 7) * 8;
        bv2[p] = *(const bf16x8*)&Wvt[(size_t)(n0 + r) * 512 + kt + c8];
      }
    }
    __syncthreads();
    *(bf16x8*)&As[ar * 72 + ac] = pack8(a4[0], a4[1]);
    *(bf16x8*)&As[ar * 72 + ac + 8] = pack8(a4[2], a4[3]);
    #pragma unroll
    for (int p = 0; p < 2; p++) {
      int f = p * 256 + t, r = f >> 3, c8 = (f & 7) * 8;
      *(bf16x8*)&Bs[r * 72 + c8] = bk[p];
    }
    if (!isQ) {
      #pragma unroll
      for (int p = 0; p < 2; p++) {
        int f = p * 256 + t, r = f >> 3, c8 = (f & 7) * 8;
        *(bf16x8*)&Bs2[r * 72 + c8] = bv2[p];
      }
    }
    __syncthreads();
    #pragma unroll
    for (int ks = 0; ks < 2; ks++) {
      bf16x8 a0 = *(const bf16x8*)&As[(ms + li) * 72 + ks * 32 + g * 8];
      bf16x8 a1 = *(const bf16x8*)&As[(ms + 16 + li) * 72 + ks * 32 + g * 8];
      bf16x8 k0 = *(const bf16x8*)&Bs[(ns + li) * 72 + ks * 32 + g * 8];
      bf16x8 k1 = *(const bf16x8*)&Bs[(ns + 16 + li) * 72 + ks * 32 + g * 8];
      acc[0][0] = MFMA16(a0, k0, acc[0][0]);
      acc[0][1] = MFMA16(a0, k1, acc[0][1]);
      acc[1][0] = MFMA16(a1, k0, acc[1][0]);
      acc[1][1] = MFMA16(a1, k1, acc[1][1]);
      if (!isQ) {
        bf16x8 v0 = *(const bf16x8*)&Bs2[(ns + li) * 72 + ks * 32 + g * 8];
        bf16x8 v1 = *(const bf16x8*)&Bs2[(ns + 16 + li) * 72 + ks * 32 + g * 8];
        accV[0][0] = MFMA16(a0, v0, accV[0][0]);
        accV[0][1] = MFMA16(a0, v1, accV[0][1]);
        accV[1][0] = MFMA16(a1, v0, accV[1][0]);
        accV[1][1] = MFMA16(a1, v1, accV[1][1]);
      }
    }
  }
  #pragma unroll
  for (int mi = 0; mi < 2; mi++) {
    #pragma unroll
    for (int ni = 0; ni < 2; ni++) {
      int row = m0 + ms + mi * 16 + 4 * g;
      int col = n0 + ns + ni * 16 + li;
      f32x4 vk = acc[mi][ni];
      if (isQ) {
        #pragma unroll
        for (int r = 0; r < 4; r++) Qp[(size_t)(row + r) * 512 + col] = bfs(vk[r]);
      } else {
        #pragma unroll
        for (int r = 0; r < 4; r++) Kp[(size_t)(row + r) * 512 + col] = bfs(vk[r]);
        f32x4 vv = accV[mi][ni];
        int bb = row >> 11, j = row & 2047;
        int hh = col >> 6, d = col & 63;
        uint2 o;
        o.x = pk2(vv[0], vv[1]);
        o.y = pk2(vv[2], vv[3]);
        *(uint2*)&Vtp[((size_t)((bb * 8 + hh) * 64 + d)) * 2048 + j] = o;
      }
    }
  }
}

// -------- fixed-max flash attention, split-K x4, per-head poly bias --------
// grid (64, 8, 2): x = qt*4 + split; 4 waves/block, wave = 16 q-rows
__global__ __launch_bounds__(256, 4) void attn_kernel(
    const u16* __restrict__ Qb, const u16* __restrict__ Kb,
    const u16* __restrict__ Vt, const float* __restrict__ qc,
    const u16* __restrict__ keg, const float* __restrict__ polyc,
    float* __restrict__ Op, float* __restrict__ Lp) {
  __shared__ u16 Kl[64 * 72];
  __shared__ u16 Vtl[64 * 72];
  __shared__ u16 Pl[64 * 72];

  const int t = threadIdx.x;
  const int w = t >> 6, l = t & 63, g = l >> 4, li = l & 15;
  const int qt = blockIdx.x >> 2, sidx = blockIdx.x & 3;
  const int h = blockIdx.y, b = blockIdx.z;

  // per-head Newton coefficients (uniform -> scalar regs)
  const float c0 = polyc[h * 8 + 0], c1 = polyc[h * 8 + 1];
  const float c2 = polyc[h * 8 + 2], c3 = polyc[h * 8 + 3];
  const float c4 = polyc[h * 8 + 4], c5 = polyc[h * 8 + 5];

  const int qrow = qt * 64 + w * 16 + li;
  const size_t qg = (size_t)b * NQ + qrow;
  bf16x8 qf0 = *(const bf16x8*)&Qb[qg * 512 + h * 64 + g * 8];
  bf16x8 qf1 = *(const bf16x8*)&Qb[qg * 512 + h * 64 + 32 + g * 8];
  float qx = qc[qg * 3], qy = qc[qg * 3 + 1], qz = qc[qg * 3 + 2];
  bf16x8 qe = {};
  if (g == 0) {
    qe[0] = (short)f2us(qx);
    qe[1] = (short)f2us(qy);
    qe[2] = (short)f2us(qz);
    qe[3] = (short)f2us(qx * qx + qy * qy + qz * qz);
    qe[4] = (short)f2us(1.0f);
  }

  f32x4 oacc[4] = {};
  float lacc = 0.0f;

  const u16* Kg = Kb + (size_t)b * NK * 512 + h * 64;
  const u16* Vg = Vt + (size_t)((b * 8 + h) * 64) * 2048;
  const u16* keg_b = keg + (size_t)b * NK * 8;

  for (int it = 0; it < 8; it++) {
    const int jbase = sidx * 512 + it * 64;
    __syncthreads();
    #pragma unroll
    for (int pp = 0; pp < 2; pp++) {
      int f = pp * 256 + t, row = f >> 3, c8 = (f & 7) * 8;
      *(bf16x8*)&Kl[row * 72 + c8] =
          *(const bf16x8*)&Kg[(size_t)(jbase + row) * 512 + c8];
      *(bf16x8*)&Vtl[row * 72 + c8] =
          *(const bf16x8*)&Vg[(size_t)row * 2048 + jbase + c8];
    }
    __syncthreads();

    // S^T = K Q^T and d^2 via augmented MFMA (col=i=li, row=j=4g+r)
    f32x4 sac[4], dac[4];
    #pragma unroll
    for (int j4 = 0; j4 < 4; j4++) {
      bf16x8 ka0 = *(const bf16x8*)&Kl[(j4 * 16 + li) * 72 + g * 8];
      bf16x8 ka1 = *(const bf16x8*)&Kl[(j4 * 16 + li) * 72 + 32 + g * 8];
      f32x4 z = {};
      f32x4 s0 = MFMA16(ka0, qf0, z);
      sac[j4] = MFMA16(ka1, qf1, s0);
      bf16x8 ke = {};
      if (g == 0)
        ke = *(const bf16x8*)&keg_b[(size_t)(jbase + j4 * 16 + li) * 8];
      dac[j4] = MFMA16(ke, qe, z);
    }

    // p = exp2(s*SC2 + g(d)); fast transcendentals, integer bf16 pack
    #pragma unroll
    for (int j4 = 0; j4 < 4; j4++) {
      float p[4];
      #pragma unroll
      for (int r = 0; r < 4; r++) {
        float u = fmaxf(dac[j4][r], 0.0f);
        float d = fminf(__builtin_amdgcn_sqrtf(u), 16.0f);
        float gp = c5;
        gp = fmaf(gp, d - XN4, c4);
        gp = fmaf(gp, d - XN3, c3);
        gp = fmaf(gp, d - XN2, c2);
        gp = fmaf(gp, d - XN1, c1);
        gp = fmaf(gp, d - XN0, c0);
        p[r] = __builtin_amdgcn_exp2f(fmaf(sac[j4][r], SC2, gp));
        lacc += p[r];
      }
      uint2 pv;
      pv.x = pk2(p[0], p[1]);
      pv.y = pk2(p[2], p[3]);
      *(uint2*)&Pl[(w * 16 + li) * 72 + j4 * 16 + g * 4] = pv;
    }

    // PV (wave-local Pl roundtrip)
    bf16x8 pf0 = *(const bf16x8*)&Pl[(w * 16 + li) * 72 + g * 8];
    bf16x8 pf1 = *(const bf16x8*)&Pl[(w * 16 + li) * 72 + 32 + g * 8];
    #pragma unroll
    for (int dt = 0; dt < 4; dt++) {
      bf16x8 v0 = *(const bf16x8*)&Vtl[(dt * 16 + li) * 72 + g * 8];
      bf16x8 v1 = *(const bf16x8*)&Vtl[(dt * 16 + li) * 72 + 32 + g * 8];
      oacc[dt] = MFMA16(pf0, v0, oacc[dt]);
      oacc[dt] = MFMA16(pf1, v1, oacc[dt]);
    }
  }

  float lf = lacc;
  lf += __shfl_xor(lf, 16);
  lf += __shfl_xor(lf, 32);

  const size_t obase =
      ((size_t)(sidx * 16 + b * 8 + h) * 1024 + qt * 64 + w * 16) * 64;
  #pragma unroll
  for (int dt = 0; dt < 4; dt++)
    #pragma unroll
    for (int r = 0; r < 4; r++)
      Op[obase + (size_t)(4 * g + r) * 64 + dt * 16 + li] = oacc[dt][r];
  if (g == 0)
    Lp[(size_t)(sidx * 16 + b * 8 + h) * 1024 + qt * 64 + w * 16 + li] = lf;
}

// ------- Wo GEMM with inline split-combine: C = combine(Op,Lp) @ Wot^T -----
// grid (64, 8), TM=32; A-tile staged from 4 split partials, normalized
__global__ __launch_bounds__(256) void gemm_wo(const float* __restrict__ Op,
                                               const float* __restrict__ Lp,
                                               const u16* __restrict__ Bt,
                                               float* __restrict__ C) {
  __shared__ u16 As[32 * 72];
  __shared__ u16 Bs[64 * 72];
  const int t = threadIdx.x;
  const int w = t >> 6, l = t & 63, g = l >> 4, li = l & 15;
  const int m0 = blockIdx.x * 32, n0 = blockIdx.y * 64;
  const int ms = (w & 1) * 16, ns = (w >> 1) * 32;
  // A staging map: row r = t>>3 (32 rows), d-cols c8..c8+8
  const int arow = t >> 3, ac8 = (t & 7) * 8;
  const int bq = (m0 + arow) >> 10, qrow = (m0 + arow) & 1023;
  f32x4 acc[2] = {};

  for (int kt = 0; kt < 512; kt += 64) {
    const int h = kt >> 6;
    const int bh = bq * 8 + h;
    f32x4 s0 = {}, s1 = {};
    float lsum = 0.0f;
    #pragma unroll
    for (int s = 0; s < 4; s++) {
      const float* base = &Op[((size_t)(s * 16 + bh) * 1024 + qrow) * 64 + ac8];
      s0 += *(const f32x4*)base;
      s1 += *(const f32x4*)(base + 4);
      lsum += Lp[(size_t)(s * 16 + bh) * 1024 + qrow];
    }
    float inv = __builtin_amdgcn_rcpf(lsum);
    bf16x8 bv[2];
    #pragma unroll
    for (int p = 0; p < 2; p++) {
      int f = p * 256 + t, r = f >> 3, c8 = (f & 7) * 8;
      bv[p] = *(const bf16x8*)&Bt[(size_t)(n0 + r) * 512 + kt + c8];
    }
    __syncthreads();
    {
      union { bf16x8 v; uint4 u; } cv;
      cv.u.x = pk2(s0[0] * inv, s0[1] * inv);
      cv.u.y = pk2(s0[2] * inv, s0[3] * inv);
      cv.u.z = pk2(s1[0] * inv, s1[1] * inv);
      cv.u.w = pk2(s1[2] * inv, s1[3] * inv);
      *(bf16x8*)&As[arow * 72 + ac8] = cv.v;
    }
    #pragma unroll
    for (int p = 0; p < 2; p++) {
      int f = p * 256 + t, r = f >> 3, c8 = (f & 7) * 8;
      *(bf16x8*)&Bs[r * 72 + c8] = bv[p];
    }
    __syncthreads();
    #pragma unroll
    for (int ks = 0; ks < 2; ks++) {
      bf16x8 af = *(const bf16x8*)&As[(ms + li) * 72 + ks * 32 + g * 8];
      bf16x8 b0 = *(const bf16x8*)&Bs[(ns + li) * 72 + ks * 32 + g * 8];
      bf16x8 b1 = *(const bf16x8*)&Bs[(ns + 16 + li) * 72 + ks * 32 + g * 8];
      acc[0] = MFMA16(af, b0, acc[0]);
      acc[1] = MFMA16(af, b1, acc[1]);
    }
  }
  #pragma unroll
  for (int ni = 0; ni < 2; ni++) {
    f32x4 v = acc[ni];
    int row = m0 + ms + 4 * g;
    int col = n0 + ns + ni * 16 + li;
    #pragma unroll
    for (int r = 0; r < 4; r++) C[(size_t)(row + r) * 512 + col] = v[r];
  }
}

extern "C" void kernel_launch(void* const* d_in, const int* in_sizes, int n_in,
                              void* d_out, int out_size, void* d_ws, size_t ws_size,
                              hipStream_t stream) {
  const float* q_in      = (const float*)d_in[0];
  const float* kv_in     = (const float*)d_in[1];
  const float* q_coords  = (const float*)d_in[2];
  const float* kv_coords = (const float*)d_in[3];
  const float* Wq        = (const float*)d_in[4];
  const float* Wk        = (const float*)d_in[5];
  const float* Wv        = (const float*)d_in[6];
  const float* Wo        = (const float*)d_in[7];
  const float* W1        = (const float*)d_in[8];
  const float* b1        = (const float*)d_in[9];
  const float* W2        = (const float*)d_in[10];
  const float* b2        = (const float*)d_in[11];

  char* p = (char*)d_ws;
  u16* Wqt  = (u16*)p; p += (size_t)512 * 512 * 2;
  u16* Wkt  = (u16*)p; p += (size_t)512 * 512 * 2;
  u16* Wvt  = (u16*)p; p += (size_t)512 * 512 * 2;
  u16* Wot  = (u16*)p; p += (size_t)512 * 512 * 2;
  u16* Qp   = (u16*)p; p += (size_t)2048 * 512 * 2;
  u16* Kp   = (u16*)p; p += (size_t)4096 * 512 * 2;
  u16* Vtp  = (u16*)p; p += (size_t)4096 * 512 * 2;
  u16* keg  = (u16*)p; p += (size_t)4096 * 8 * 2;
  float* polyc = (float*)p; p += (size_t)64 * 4;
  p = (char*)(((size_t)p + 255) & ~(size_t)255);
  float* Opart = (float*)p; p += (size_t)4 * 16 * 1024 * 64 * 4;
  float* Lpart = (float*)p; p += (size_t)4 * 16 * 1024 * 4;

  setup_kernel<<<273, 256, 0, stream>>>(Wq, Wk, Wv, Wo, Wqt, Wkt, Wvt, Wot,
                                        W1, b1, W2, b2, polyc, kv_coords, keg);
  gemm_qkv<<<dim3(96, 8), 256, 0, stream>>>(q_in, kv_in, Wqt, Wkt, Wvt,
                                            Qp, Kp, Vtp);
  attn_kernel<<<dim3(64, 8, 2), 256, 0, stream>>>(Qp, Kp, Vtp, q_coords, keg,
                                                  polyc, Opart, Lpart);
  gemm_wo<<<dim3(64, 8), 256, 0, stream>>>(Opart, Lpart, Wot, (float*)d_out);
}